// Round 12
// baseline (402.588 us; speedup 1.0000x reference)
//
#include <hip/hip_runtime.h>
#include <math.h>

// Problem constants (reference: B=2,S=1024,E=1024,H=8,D=128,L=3)
#define BDIM 2
#define SDIM 1024
#define EDIM 1024
#define HDIM 8
#define DDIM 128
#define LNUM 3
#define NZ 16
#define NPART 4
#define SCALE_F 0.08838834764831845f
#define QSCALE_L2E 0.12751742f     // SCALE * log2(e)
#define TWO_L2E 2.8853901f         // 2 * log2(e)

// WORLD MODEL (verified R6-R11): complex64 lowered to f32 REAL-PART-ONLY.
// Precision: residual `cur` bf16x3 (h+l); everything else single bf16.
// R12: no-max softmax + exp2; weight folds; expmap fused in qkv epilogue.
// R13/R14 (REGRESSED): cross-barrier reg prefetch (32 VGPR) spilled.
// R15 (WIN, 477): flash K/V via global_load_lds w16 + pre-swizzled source.
// R16/R17 (WIN, 422.8): 64-row gemm tiles double block count.
// R18/R19 (REG/NEUTRAL, 457): gload_lds in gemm loses to reg-staging.
// R20 (WIN, 404.7): reg-staged gemm; Opart bf16 banked.
// R21 (WIN, 377.9): BK 32->64 halves per-block barrier/drain count.
// R22 (SEVERE REG, 696.8): BK=128 staging (12 uint4) spilled. BK sweep
// closed {32:405, 64:378, 128:spill} -> BK=64 final.
// R23 (OK, 383.4 ~= R21 within fill noise): revert confirmed.
// R24: (a) flash_part QBLK 64->128 (2 q-groups/wave): same K/V staging
// serves 2x MFMA; kb/vb LDS fragments loaded once, used for both groups;
// barriers/work halved. LDS 48KB (3 blocks/CU), grid 512. Accumulator
// VGPRs (oacc 64) are benign — spill risk was STAGING regs (R13/R22).
// Watch: flash VGPR<=~190, WRITE_SIZE ~17MB. (b) vectorized combine
// (bf16x8, 8 elem/thread, 1024 blocks).

typedef unsigned short u16;
typedef __attribute__((ext_vector_type(8))) short bf16x8;
typedef __attribute__((ext_vector_type(4))) float f32x4;
typedef __attribute__((address_space(3))) unsigned char lds_u8;
typedef __attribute__((address_space(1))) const unsigned char glob_u8;

__device__ __forceinline__ u16 bf16_rne(float x) {
    unsigned u = __float_as_uint(x);
    u += 0x7FFFu + ((u >> 16) & 1u);
    return (u16)(u >> 16);
}
__device__ __forceinline__ float bf16f(u16 h) {
    return __uint_as_float(((unsigned)h) << 16);
}

// ---------------------------------------------------------------------------
__global__ __launch_bounds__(256) void split_k(
    const float* __restrict__ in, u16* __restrict__ h, u16* __restrict__ l,
    long long n4)
{
    long long i = (long long)blockIdx.x * 256 + threadIdx.x;
    if (i >= n4) return;
    float4 v = ((const float4*)in)[i];
    float vv[4] = { v.x, v.y, v.z, v.w };
    u16 hh[4], ll[4];
#pragma unroll
    for (int j = 0; j < 4; j++) {
        hh[j] = bf16_rne(vv[j]);
        ll[j] = bf16_rne(vv[j] - bf16f(hh[j]));
    }
    ((uint2*)h)[i] = make_uint2((unsigned)hh[0] | ((unsigned)hh[1] << 16),
                                (unsigned)hh[2] | ((unsigned)hh[3] << 16));
    ((uint2*)l)[i] = make_uint2((unsigned)ll[0] | ((unsigned)ll[1] << 16),
                                (unsigned)ll[2] | ((unsigned)ll[3] << 16));
}

// h-plane-only split (weights: l-plane is discarded anyway).
__global__ __launch_bounds__(256) void splith_k(
    const float* __restrict__ in, u16* __restrict__ h, long long n4)
{
    long long i = (long long)blockIdx.x * 256 + threadIdx.x;
    if (i >= n4) return;
    float4 v = ((const float4*)in)[i];
    ((uint2*)h)[i] = make_uint2(
        (unsigned)bf16_rne(v.x) | ((unsigned)bf16_rne(v.y) << 16),
        (unsigned)bf16_rne(v.z) | ((unsigned)bf16_rne(v.w) << 16));
}

// Batched split for the three DxD head weights (h-plane only). 48 blocks.
__global__ __launch_bounds__(256) void split3_k(
    const float* __restrict__ a, const float* __restrict__ b,
    const float* __restrict__ c, u16* __restrict__ h)
{
    const int t = blockIdx.x >> 4;                 // 0..2
    const float* src = (t == 0) ? a : (t == 1) ? b : c;
    const long long i = (long long)(blockIdx.x & 15) * 256 + threadIdx.x; // [0,4096)
    float4 v = ((const float4*)src)[i];
    u16* hp = h + (long long)t * 16384;
    ((uint2*)hp)[i] = make_uint2(
        (unsigned)bf16_rne(v.x) | ((unsigned)bf16_rne(v.y) << 16),
        (unsigned)bf16_rne(v.z) | ((unsigned)bf16_rne(v.w) << 16));
}

// ---------------------------------------------------------------------------
// Single-bf16 GEMM, tile 64 x NT x 64 (BK=64, R21 proven), 256 thr (4 waves
// 2x2), acc[2][NT/32]. Reg-staged same-iteration staging.
// C[m,n] = alpha*sum_k A[m,k]*B[n,k] (+Ch+Cl if accum). storeL: write l-plane.
// doExp (NT==128 only): zp==0/1 -> expmap0 per output row in-epilogue.
// K must be a multiple of 64.
// ---------------------------------------------------------------------------
template<int NT>
__global__ __launch_bounds__(256) void gemm_t(
    const u16* __restrict__ Ah,
    long long aOff, int lda, long long aSP, long long aSB, long long aSH,
    const u16* __restrict__ Bh,
    long long bOff, int ldb, long long bSP, long long bSB, long long bSH,
    u16* __restrict__ Ch, u16* __restrict__ Cl,
    long long cOff, int ldc, long long cSP, long long cSB, long long cSH,
    int Bdec, int Hdec, int K, float alpha, int accum, int storeL, int doExp)
{
    constexpr int NJ = NT / 32;                   // j-tiles per wave
    __shared__ __align__(16) u16 AhL[8][64][8];   // kp 0..7
    __shared__ __align__(16) u16 BhL[8][NT][8];
    __shared__ float rsum[64][2];

    const int tid  = threadIdx.x;
    const int lane = tid & 63;
    const int wave = tid >> 6;
    const int quad = lane >> 4;
    const int l16  = lane & 15;
    const int z  = blockIdx.z;
    const int zp = z / (Bdec * Hdec);
    const int r  = z - zp * Bdec * Hdec;
    const int zb = r / Hdec, zh = r - zb * Hdec;
    const long long aBase = aOff + (long long)zp * aSP + (long long)zb * aSB + (long long)zh * aSH;
    const long long bBase = bOff + (long long)zp * bSP + (long long)zb * bSB + (long long)zh * bSH;
    const long long cBase = cOff + (long long)zp * cSP + (long long)zb * cSB + (long long)zh * cSH;
    const int bm = blockIdx.y * 64, bn = blockIdx.x * NT;
    const int wr = (wave >> 1) * 32, wc = (wave & 1) * (NT / 2);

    // A staging: two uint4/thread. row = tid>>2, k-planes (tid&3), (tid&3)+4.
    const int ar = tid >> 2, ap = tid & 3;
    const u16* gA = Ah + aBase + (long long)(bm + ar) * lda + ap * 8;

    // B staging: NT=128 -> four uint4/thread; NT=64 -> two.
    const int sm = tid >> 1, kh = (tid & 1) * 16, c0 = kh >> 3;   // NT=128
    const int br = tid >> 2, bp = tid & 3;                        // NT=64
    const u16* gB = (NT == 128)
        ? Bh + bBase + (long long)(bn + sm) * ldb + kh
        : Bh + bBase + (long long)(bn + br) * ldb + bp * 8;

    f32x4 acc[2][NJ];
#pragma unroll
    for (int i = 0; i < 2; i++)
#pragma unroll
        for (int j = 0; j < NJ; j++) {
            acc[i][j][0] = 0.f; acc[i][j][1] = 0.f;
            acc[i][j][2] = 0.f; acc[i][j][3] = 0.f;
        }

    for (int k0 = 0; k0 < K; k0 += 64) {
        uint4 a0 = *(const uint4*)(gA + k0);
        uint4 a1 = *(const uint4*)(gA + k0 + 32);
        uint4 b0, b1, b2, b3;
        b0 = *(const uint4*)(gB + k0);
        b2 = *(const uint4*)(gB + k0 + 32);
        if (NT == 128) {
            b1 = *(const uint4*)(gB + k0 + 8);
            b3 = *(const uint4*)(gB + k0 + 40);
        }
        __syncthreads();
        *(uint4*)&AhL[ap][ar][0]     = a0;
        *(uint4*)&AhL[ap + 4][ar][0] = a1;
        if (NT == 128) {
            *(uint4*)&BhL[c0][sm][0]     = b0;
            *(uint4*)&BhL[c0 + 1][sm][0] = b1;
            *(uint4*)&BhL[c0 + 4][sm][0] = b2;
            *(uint4*)&BhL[c0 + 5][sm][0] = b3;
        } else {
            *(uint4*)&BhL[bp][br][0]     = b0;
            *(uint4*)&BhL[bp + 4][br][0] = b2;
        }
        __syncthreads();

#pragma unroll
        for (int s = 0; s < 2; s++) {
            bf16x8 fah[2], fbh[NJ];
#pragma unroll
            for (int i = 0; i < 2; i++)
                fah[i] = *(const bf16x8*)&AhL[s * 4 + quad][wr + i * 16 + l16][0];
#pragma unroll
            for (int j = 0; j < NJ; j++)
                fbh[j] = *(const bf16x8*)&BhL[s * 4 + quad][wc + j * 16 + l16][0];
#pragma unroll
            for (int i = 0; i < 2; i++)
#pragma unroll
                for (int j = 0; j < NJ; j++)
                    acc[i][j] = __builtin_amdgcn_mfma_f32_16x16x32_bf16(fah[i], fbh[j], acc[i][j], 0, 0, 0);
        }
    }

    // ---- optional fused expmap0 (q/k slices of the qkv projection) ----
    if (NT == 128 && doExp && zp < 2) {
        const float qs = (zp == 0) ? QSCALE_L2E : 1.0f;
#pragma unroll
        for (int i = 0; i < 2; i++)
#pragma unroll
            for (int rr = 0; rr < 4; rr++) {
                float ps = 0.f;
#pragma unroll
                for (int j = 0; j < NJ; j++) {
                    float v = acc[i][j][rr];
                    ps += v * v;
                }
                ps += __shfl_xor(ps, 1, 64); ps += __shfl_xor(ps, 2, 64);
                ps += __shfl_xor(ps, 4, 64); ps += __shfl_xor(ps, 8, 64);
                if (l16 == 0) rsum[wr + i * 16 + quad * 4 + rr][wc >> 6] = ps;
            }
        __syncthreads();
#pragma unroll
        for (int i = 0; i < 2; i++)
#pragma unroll
            for (int rr = 0; rr < 4; rr++) {
                int m = wr + i * 16 + quad * 4 + rr;
                float n2 = rsum[m][0] + rsum[m][1];
                float nn = fmaxf(sqrtf(n2), 1e-6f);
                float e2 = exp2f(TWO_L2E * nn);          // e^{2n}
                float scl = (1.f - 2.f / (e2 + 1.f)) / nn * qs;  // tanh(n)/n * qs
#pragma unroll
                for (int j = 0; j < NJ; j++) acc[i][j][rr] *= scl;
            }
    }

#pragma unroll
    for (int i = 0; i < 2; i++)
#pragma unroll
        for (int j = 0; j < NJ; j++)
#pragma unroll
            for (int rr = 0; rr < 4; rr++) {
                int m = bm + wr + i * 16 + quad * 4 + rr;
                int n = bn + wc + j * 16 + l16;
                long long ci = cBase + (long long)m * ldc + n;
                float c = acc[i][j][rr] * alpha;
                if (accum) c += bf16f(Ch[ci]) + bf16f(Cl[ci]);
                u16 hh = bf16_rne(c);
                Ch[ci] = hh;
                if (storeL) Cl[ci] = bf16_rne(c - bf16f(hh));
            }
}

// ---------------------------------------------------------------------------
// Flash split-K partial, no-max softmax (bounded logits; Q pre-scaled by
// SCALE*log2e so P = exp2(sacc)). Emits unnormalized O_p (bf16) + l_p.
// R24: QBLK=128 (2 q-groups per wave). K/V staged once per ti serve both
// groups; kb/vb LDS fragments shared. K/V via global_load_lds w16 with
// pre-swizzled source; 48KB LDS.
// ---------------------------------------------------------------------------
__global__ __launch_bounds__(256) void flash_part(
    const u16* __restrict__ Qh, const u16* __restrict__ Kh,
    const u16* __restrict__ Vth,
    u16* __restrict__ Opart, float* __restrict__ Lpart)
{
    __shared__ __align__(16) u16 Kls[64 * 128];   // [key 64][d 128], swizzled
    __shared__ __align__(16) u16 Vls[128 * 64];   // [d 128][key 64], swizzled
    __shared__ __align__(16) u16 pls[128 * 64];   // [qrow 128][key 64], swizzled

    const int tid  = threadIdx.x;
    const int lane = tid & 63;
    const int w    = tid >> 6;
    const int quad = lane >> 4;
    const int l16  = lane & 15;
    const int z    = blockIdx.z;
    const int part = blockIdx.y;
    const int q0   = blockIdx.x * 128;
    const long long zoff = (long long)z * SDIM * DDIM;
    const int pz = part * NZ + z;
    const int sw = (l16 & 7) << 4;                // read-side swizzle (row&7)==(l16&7)

    // ---- global_load_lds staging geometry (pre-swizzled global source) ----
    const u16* kgp[4];
    const u16* vgp[4];
#pragma unroll
    for (int i = 0; i < 4; i++) {
        int rk = w * 16 + i * 4 + (lane >> 4);
        int sk = (lane & 15) ^ (rk & 7);
        kgp[i] = Kh + zoff + (long long)(part * 256 + rk) * DDIM + sk * 8;
        int rv = w * 32 + i * 8 + (lane >> 3);
        int sv = (lane & 7) ^ (rv & 7);
        vgp[i] = Vth + zoff + (long long)rv * SDIM + part * 256 + sv * 8;
    }

    // Q: wave w owns rows q0 + w*32 + g*16 + l16, g in {0,1}
    bf16x8 qf[2][4];
#pragma unroll
    for (int g = 0; g < 2; g++) {
        const u16* qr = Qh + zoff + (long long)(q0 + w * 32 + g * 16 + l16) * DDIM;
#pragma unroll
        for (int s = 0; s < 4; s++) qf[g][s] = *(const bf16x8*)(qr + s * 32 + quad * 8);
    }

    f32x4 oacc[2][8];
#pragma unroll
    for (int g = 0; g < 2; g++)
#pragma unroll
        for (int dt = 0; dt < 8; dt++) {
            oacc[g][dt][0] = 0.f; oacc[g][dt][1] = 0.f;
            oacc[g][dt][2] = 0.f; oacc[g][dt][3] = 0.f;
        }
    float lp[2][4] = { { 0.f, 0.f, 0.f, 0.f }, { 0.f, 0.f, 0.f, 0.f } };

    for (int ti = 0; ti < 4; ti++) {
        __syncthreads();                          // prior compute done reading LDS
#pragma unroll
        for (int i = 0; i < 4; i++) {
            __builtin_amdgcn_global_load_lds(
                (glob_u8*)kgp[i], (lds_u8*)&Kls[w * 2048 + i * 512], 16, 0, 0);
            __builtin_amdgcn_global_load_lds(
                (glob_u8*)vgp[i], (lds_u8*)&Vls[w * 2048 + i * 512], 16, 0, 0);
            kgp[i] += 64 * DDIM;                  // next key-tile (K rows)
            vgp[i] += 64;                         // next key-tile (V cols)
        }
        __syncthreads();                          // vmcnt(0) drained -> tiles visible

        // ---- QK^T (kb shared across both q-groups) ----
        f32x4 sacc[2][4];
        __builtin_amdgcn_s_setprio(1);
#pragma unroll
        for (int ct = 0; ct < 4; ct++) {
            f32x4 a0, a1;
            a0[0] = 0.f; a0[1] = 0.f; a0[2] = 0.f; a0[3] = 0.f;
            a1 = a0;
            const char* kb_row = (const char*)Kls + (ct * 16 + l16) * 256;
#pragma unroll
            for (int s = 0; s < 4; s++) {
                bf16x8 kb = *(const bf16x8*)(kb_row + (((s * 64) | (quad * 16)) ^ sw));
                a0 = __builtin_amdgcn_mfma_f32_16x16x32_bf16(qf[0][s], kb, a0, 0, 0, 0);
                a1 = __builtin_amdgcn_mfma_f32_16x16x32_bf16(qf[1][s], kb, a1, 0, 0, 0);
            }
            sacc[0][ct] = a0;
            sacc[1][ct] = a1;
        }
        __builtin_amdgcn_s_setprio(0);

        // P = exp2(sacc); accumulate per-thread row partials (no max needed)
#pragma unroll
        for (int g = 0; g < 2; g++)
#pragma unroll
            for (int ct = 0; ct < 4; ct++)
#pragma unroll
                for (int r = 0; r < 4; r++) {
                    float p = exp2f(sacc[g][ct][r]);
                    lp[g][r] += p;
                    int prow = w * 32 + g * 16 + quad * 4 + r;
                    int pcol = ct * 16 + l16;
                    *(u16*)((char*)pls + prow * 128 + ((pcol * 2) ^ ((prow & 7) << 4))) = bf16_rne(p);
                }

        bf16x8 pa[2][2];
#pragma unroll
        for (int g = 0; g < 2; g++) {
            const char* p_row = (const char*)pls + (w * 32 + g * 16 + l16) * 128;
#pragma unroll
            for (int ks2 = 0; ks2 < 2; ks2++)
                pa[g][ks2] = *(const bf16x8*)(p_row + (((ks2 * 64) | (quad * 16)) ^ sw));
        }

        // ---- PV (vb shared across both q-groups) ----
        __builtin_amdgcn_s_setprio(1);
#pragma unroll
        for (int dt = 0; dt < 8; dt++) {
            f32x4 o0 = oacc[0][dt], o1 = oacc[1][dt];
            const char* v_row = (const char*)Vls + (dt * 16 + l16) * 128;
#pragma unroll
            for (int ks2 = 0; ks2 < 2; ks2++) {
                bf16x8 vb = *(const bf16x8*)(v_row + (((ks2 * 64) | (quad * 16)) ^ sw));
                o0 = __builtin_amdgcn_mfma_f32_16x16x32_bf16(pa[0][ks2], vb, o0, 0, 0, 0);
                o1 = __builtin_amdgcn_mfma_f32_16x16x32_bf16(pa[1][ks2], vb, o1, 0, 0, 0);
            }
            oacc[0][dt] = o0;
            oacc[1][dt] = o1;
        }
        __builtin_amdgcn_s_setprio(0);
    }

    const long long obase = (long long)pz * SDIM * DDIM;
#pragma unroll
    for (int g = 0; g < 2; g++)
#pragma unroll
        for (int dt = 0; dt < 8; dt++)
#pragma unroll
            for (int r = 0; r < 4; r++) {
                int srow = q0 + w * 32 + g * 16 + quad * 4 + r;
                Opart[obase + (long long)srow * DDIM + dt * 16 + l16] = bf16_rne(oacc[g][dt][r]);
            }
#pragma unroll
    for (int g = 0; g < 2; g++)
#pragma unroll
        for (int r = 0; r < 4; r++) {
            float s = lp[g][r];
            s += __shfl_xor(s, 1, 64); s += __shfl_xor(s, 2, 64);
            s += __shfl_xor(s, 4, 64); s += __shfl_xor(s, 8, 64);
            if (l16 == 0) {
                int srow = q0 + w * 32 + g * 16 + quad * 4 + r;
                Lpart[(long long)pz * SDIM + srow] = s;
            }
        }
}

// ---------------------------------------------------------------------------
// Combine: O = sum_p O_p / sum_p l_p. Vectorized: 8 elem/thread (bf16x8).
// grid 1024 x 256 thr; thread i -> row i/16, d-slice (i%16)*8.
// ---------------------------------------------------------------------------
__global__ __launch_bounds__(256) void flash_combine(
    const u16* __restrict__ Opart, const float* __restrict__ Lpart,
    u16* __restrict__ Oh)
{
    const long long i = (long long)blockIdx.x * 256 + threadIdx.x;  // 0..262143
    const int rg = (int)(i >> 4);                 // 0..16383 = z*1024+row
    const int z = rg >> 10, row = rg & 1023;
    const int d0 = ((int)i & 15) * 8;
    float lt = 0.f;
#pragma unroll
    for (int p = 0; p < NPART; p++)
        lt += Lpart[(long long)(p * NZ + z) * SDIM + row];
    const float inv = 1.f / lt;
    float o[8] = { 0.f, 0.f, 0.f, 0.f, 0.f, 0.f, 0.f, 0.f };
#pragma unroll
    for (int p = 0; p < NPART; p++) {
        bf16x8 v = *(const bf16x8*)&Opart[
            (long long)(p * NZ + z) * SDIM * DDIM + (long long)row * DDIM + d0];
#pragma unroll
        for (int j = 0; j < 8; j++) o[j] += bf16f((u16)v[j]);
    }
    unsigned w4[4];
#pragma unroll
    for (int j = 0; j < 4; j++)
        w4[j] = (unsigned)bf16_rne(o[2 * j] * inv)
              | ((unsigned)bf16_rne(o[2 * j + 1] * inv) << 16);
    const int b = z >> 3, h = z & 7;
    *(uint4*)&Oh[(long long)b * SDIM * EDIM + (long long)row * EDIM + h * DDIM + d0] =
        make_uint4(w4[0], w4[1], w4[2], w4[3]);
}

// ---------------------------------------------------------------------------
// Generic 64x64-tile transpose. grid (rT, cT, nz).
// ---------------------------------------------------------------------------
__global__ __launch_bounds__(256) void transpose_g(
    const u16* __restrict__ src, u16* __restrict__ dst,
    int ldS, int ldD, long long sZ, long long dZ)
{
    __shared__ __align__(16) u16 tl[64][72];
    const int r0 = blockIdx.x * 64, c0 = blockIdx.y * 64;
    const u16* s = src + (long long)blockIdx.z * sZ;
    u16* d = dst + (long long)blockIdx.z * dZ;
    const int t = threadIdx.x;
    const int sr = t >> 2, dc = (t & 3) * 16;
    {
        const u16* p = s + (long long)(r0 + sr) * ldS + c0 + dc;
        *(uint4*)&tl[sr][dc]     = *(const uint4*)p;
        *(uint4*)&tl[sr][dc + 8] = *(const uint4*)(p + 8);
    }
    __syncthreads();
    const int dr = t >> 2, sc = (t & 3) * 16;
    unsigned wbuf[8];
#pragma unroll
    for (int i = 0; i < 8; i++)
        wbuf[i] = (unsigned)tl[sc + 2 * i][dr] | ((unsigned)tl[sc + 2 * i + 1][dr] << 16);
    u16* po = d + (long long)(c0 + dr) * ldD + r0 + sc;
    *(uint4*)po = make_uint4(wbuf[0], wbuf[1], wbuf[2], wbuf[3]);
    *(uint4*)(po + 8) = make_uint4(wbuf[4], wbuf[5], wbuf[6], wbuf[7]);
}

// final output: f32 = h + l (zero-fill past nmax)
__global__ __launch_bounds__(256) void out_k(
    const u16* __restrict__ h, const u16* __restrict__ l,
    float* __restrict__ out, long long n, long long nmax)
{
    long long i = (long long)blockIdx.x * 256 + threadIdx.x;
    if (i < n) out[i] = (i < nmax) ? (bf16f(h[i]) + bf16f(l[i])) : 0.f;
}

#define N2   2097152LL            // B*S*E == NZ*S*D
#define W3N  3145728LL            // 3E*E
#define WON  1048576LL            // E*E
#define WHN  49152LL              // 3*D*D
#define EE   1048576LL            // E*E

extern "C" void kernel_launch(void* const* d_in, const int* in_sizes, int n_in,
                              void* d_out, int out_size, void* d_ws, size_t ws_size,
                              hipStream_t stream)
{
    const float* x       = (const float*)d_in[0];
    const float* Wqkv    = (const float*)d_in[1];
    const float* Wq      = (const float*)d_in[3];
    const float* Wk      = (const float*)d_in[5];
    const float* Wv      = (const float*)d_in[7];
    const float* Wout    = (const float*)d_in[9];
    const float* Wlayers = (const float*)d_in[11];

    u16* ws = (u16*)d_ws;
    long long o = 0;
    u16 *curh = ws + o; o += N2;  u16 *curl = ws + o; o += N2;
    u16 *qkvh = ws + o; o += 3 * N2;
    u16 *vth  = ws + o; o += N2;
    u16 *aoh  = ws + o; o += N2;
    u16 *wqh  = ws + o; o += W3N;
    u16 *wqth = ws + o; o += W3N;
    u16 *wfh  = ws + o; o += W3N;
    u16 *whh  = ws + o; o += WHN;
    u16 *woh  = ws + o; o += WON;
    u16 *woth = ws + o; o += WON;
    u16 *wlh  = ws + o; o += W3N;
    u16 *wloh = ws + o; o += W3N;
    u16 *Opart = ws + o; o += NPART * NZ * SDIM * DDIM;          // bf16
    float *Lpart = (float*)(ws + o); o += 2 * NPART * NZ * SDIM;
    // total < 184 MB

    // ---- one-time: splits (weights: h-plane only) ----
    split_k<<<2048, 256, 0, stream>>>(x, curh, curl, N2 / 4);
    splith_k<<<3072, 256, 0, stream>>>(Wqkv, wqh, W3N / 4);
    split3_k<<<48, 256, 0, stream>>>(Wq, Wk, Wv, whh);
    splith_k<<<1024, 256, 0, stream>>>(Wout, woh, WON / 4);
    splith_k<<<3072, 256, 0, stream>>>(Wlayers, wlh, W3N / 4);

    // ---- one-time: transposes (h-planes only) ----
    transpose_g<<<dim3(48, 16, 1), 256, 0, stream>>>(wqh, wqth, EDIM, 3 * EDIM, 0, 0);
    transpose_g<<<dim3(16, 16, 1), 256, 0, stream>>>(woh, woth, EDIM, EDIM, 0, 0);

    // ---- one-time: Wfused = blockdiag(Wq,Wk,Wv) @ Wqkv  (single-bf16) ----
    gemm_t<128><<<dim3(8, 2, 24), 256, 0, stream>>>(
        whh, 0, DDIM, (long long)DDIM * DDIM, 0, 0,
        wqth, 0, 3 * EDIM, EDIM, 0, DDIM,
        wfh, wfh, 0, EDIM, (long long)EDIM * EDIM, 0, (long long)DDIM * EDIM,
        1, 8, DDIM, 1.0f, 0, 0, 0);

    // ---- one-time: Wlo[l] = Wlayers[l] @ Wout  (single-bf16) ----
    gemm_t<64><<<dim3(16, 16, 3), 256, 0, stream>>>(
        wlh, 0, EDIM, EE, 0, 0,
        woth, 0, EDIM, 0, 0, 0,
        wloh, wloh, 0, EDIM, EE, 0, 0,
        1, 1, EDIM, 1.0f, 0, 0, 0);

    for (int layer = 0; layer < LNUM; layer++) {
        // qkv fused + epilogue expmap (q scaled by SCALE*log2e):
        // z = p*16 + b*8 + h: M=1024(s), N=128(d), K=1024
        gemm_t<128><<<dim3(1, 16, 48), 256, 0, stream>>>(
            curh, 0, EDIM, 0, (long long)SDIM * EDIM, 0,
            wfh, 0, EDIM, EE, 0, (long long)DDIM * EDIM,
            qkvh, qkvh, 0, DDIM, N2, (long long)HDIM * SDIM * DDIM, (long long)SDIM * DDIM,
            2, 8, EDIM, 1.0f, 0, 0, 1);

        // Vt[z][D][S] = V[z]^T
        transpose_g<<<dim3(16, 2, NZ), 256, 0, stream>>>(
            qkvh + 2 * N2, vth, DDIM, SDIM, (long long)SDIM * DDIM, (long long)SDIM * DDIM);

        // flash split-K partials + combine -> attnout (h only)
        flash_part<<<dim3(8, NPART, NZ), 256, 0, stream>>>(
            qkvh, qkvh + N2, vth, Opart, Lpart);
        flash_combine<<<1024, 256, 0, stream>>>(Opart, Lpart, aoh);

        // cur += attnout @ Wlo[layer]^T
        gemm_t<64><<<dim3(16, 32, 1), 256, 0, stream>>>(
            aoh, 0, EDIM, 0, 0, 0,
            wloh, (long long)layer * EE, EDIM, 0, 0, 0,
            curh, curl, 0, EDIM, 0, 0, 0,
            1, 1, EDIM, 1.0f, 1, 1, 0);
    }

    out_k<<<(out_size + 255) / 256, 256, 0, stream>>>(
        curh, curl, (float*)d_out, out_size, N2);
}

// Round 13
// 376.868 us; speedup vs baseline: 1.0682x; 1.0682x over previous
//
#include <hip/hip_runtime.h>
#include <math.h>

// Problem constants (reference: B=2,S=1024,E=1024,H=8,D=128,L=3)
#define BDIM 2
#define SDIM 1024
#define EDIM 1024
#define HDIM 8
#define DDIM 128
#define LNUM 3
#define NZ 16
#define NPART 4
#define SCALE_F 0.08838834764831845f
#define QSCALE_L2E 0.12751742f     // SCALE * log2(e)
#define TWO_L2E 2.8853901f         // 2 * log2(e)

// WORLD MODEL (verified R6-R11): complex64 lowered to f32 REAL-PART-ONLY.
// Precision: residual `cur` bf16x3 (h+l); everything else single bf16.
// R12: no-max softmax + exp2; weight folds; expmap fused in qkv epilogue.
// R13/R14 (REGRESSED): cross-barrier reg prefetch (32 VGPR) spilled.
// R15 (WIN, 477): flash K/V via global_load_lds w16 + pre-swizzled source.
// R16/R17 (WIN, 422.8): 64-row gemm tiles double block count.
// R18/R19 (REG/NEUTRAL, 457): gload_lds in gemm loses to reg-staging.
// R20 (WIN, 404.7): reg-staged gemm; Opart bf16 banked.
// R21 (WIN, 377.9): BK 32->64 halves per-block barrier/drain count.
// R22 (SEVERE REG, 696.8): BK=128 staging spilled. BK=64 final.
// R23 (OK, 383.4): revert confirmed; h-only splits banked.
// R24 (REG, 402.6): flash QBLK=128 cut co-residency 4->2 blocks/CU —
// serial stage phase re-exposed. Lesson: flash needs 4 blocks/CU more
// than per-block amortization (opposite of gemm, which has in-block ILP).
// R25: revert flash to R23 QBLK=64 verbatim (40960B LDS, grid 1024);
// KEEP vectorized combine (independent, bf16x8, 1024 blocks).

typedef unsigned short u16;
typedef __attribute__((ext_vector_type(8))) short bf16x8;
typedef __attribute__((ext_vector_type(4))) float f32x4;
typedef __attribute__((address_space(3))) unsigned char lds_u8;
typedef __attribute__((address_space(1))) const unsigned char glob_u8;

__device__ __forceinline__ u16 bf16_rne(float x) {
    unsigned u = __float_as_uint(x);
    u += 0x7FFFu + ((u >> 16) & 1u);
    return (u16)(u >> 16);
}
__device__ __forceinline__ float bf16f(u16 h) {
    return __uint_as_float(((unsigned)h) << 16);
}

// ---------------------------------------------------------------------------
__global__ __launch_bounds__(256) void split_k(
    const float* __restrict__ in, u16* __restrict__ h, u16* __restrict__ l,
    long long n4)
{
    long long i = (long long)blockIdx.x * 256 + threadIdx.x;
    if (i >= n4) return;
    float4 v = ((const float4*)in)[i];
    float vv[4] = { v.x, v.y, v.z, v.w };
    u16 hh[4], ll[4];
#pragma unroll
    for (int j = 0; j < 4; j++) {
        hh[j] = bf16_rne(vv[j]);
        ll[j] = bf16_rne(vv[j] - bf16f(hh[j]));
    }
    ((uint2*)h)[i] = make_uint2((unsigned)hh[0] | ((unsigned)hh[1] << 16),
                                (unsigned)hh[2] | ((unsigned)hh[3] << 16));
    ((uint2*)l)[i] = make_uint2((unsigned)ll[0] | ((unsigned)ll[1] << 16),
                                (unsigned)ll[2] | ((unsigned)ll[3] << 16));
}

// h-plane-only split (weights: l-plane is discarded anyway).
__global__ __launch_bounds__(256) void splith_k(
    const float* __restrict__ in, u16* __restrict__ h, long long n4)
{
    long long i = (long long)blockIdx.x * 256 + threadIdx.x;
    if (i >= n4) return;
    float4 v = ((const float4*)in)[i];
    ((uint2*)h)[i] = make_uint2(
        (unsigned)bf16_rne(v.x) | ((unsigned)bf16_rne(v.y) << 16),
        (unsigned)bf16_rne(v.z) | ((unsigned)bf16_rne(v.w) << 16));
}

// Batched split for the three DxD head weights (h-plane only). 48 blocks.
__global__ __launch_bounds__(256) void split3_k(
    const float* __restrict__ a, const float* __restrict__ b,
    const float* __restrict__ c, u16* __restrict__ h)
{
    const int t = blockIdx.x >> 4;                 // 0..2
    const float* src = (t == 0) ? a : (t == 1) ? b : c;
    const long long i = (long long)(blockIdx.x & 15) * 256 + threadIdx.x; // [0,4096)
    float4 v = ((const float4*)src)[i];
    u16* hp = h + (long long)t * 16384;
    ((uint2*)hp)[i] = make_uint2(
        (unsigned)bf16_rne(v.x) | ((unsigned)bf16_rne(v.y) << 16),
        (unsigned)bf16_rne(v.z) | ((unsigned)bf16_rne(v.w) << 16));
}

// ---------------------------------------------------------------------------
// Single-bf16 GEMM, tile 64 x NT x 64 (BK=64, R21 proven), 256 thr (4 waves
// 2x2), acc[2][NT/32]. Reg-staged same-iteration staging.
// C[m,n] = alpha*sum_k A[m,k]*B[n,k] (+Ch+Cl if accum). storeL: write l-plane.
// doExp (NT==128 only): zp==0/1 -> expmap0 per output row in-epilogue.
// K must be a multiple of 64.
// ---------------------------------------------------------------------------
template<int NT>
__global__ __launch_bounds__(256) void gemm_t(
    const u16* __restrict__ Ah,
    long long aOff, int lda, long long aSP, long long aSB, long long aSH,
    const u16* __restrict__ Bh,
    long long bOff, int ldb, long long bSP, long long bSB, long long bSH,
    u16* __restrict__ Ch, u16* __restrict__ Cl,
    long long cOff, int ldc, long long cSP, long long cSB, long long cSH,
    int Bdec, int Hdec, int K, float alpha, int accum, int storeL, int doExp)
{
    constexpr int NJ = NT / 32;                   // j-tiles per wave
    __shared__ __align__(16) u16 AhL[8][64][8];   // kp 0..7
    __shared__ __align__(16) u16 BhL[8][NT][8];
    __shared__ float rsum[64][2];

    const int tid  = threadIdx.x;
    const int lane = tid & 63;
    const int wave = tid >> 6;
    const int quad = lane >> 4;
    const int l16  = lane & 15;
    const int z  = blockIdx.z;
    const int zp = z / (Bdec * Hdec);
    const int r  = z - zp * Bdec * Hdec;
    const int zb = r / Hdec, zh = r - zb * Hdec;
    const long long aBase = aOff + (long long)zp * aSP + (long long)zb * aSB + (long long)zh * aSH;
    const long long bBase = bOff + (long long)zp * bSP + (long long)zb * bSB + (long long)zh * bSH;
    const long long cBase = cOff + (long long)zp * cSP + (long long)zb * cSB + (long long)zh * cSH;
    const int bm = blockIdx.y * 64, bn = blockIdx.x * NT;
    const int wr = (wave >> 1) * 32, wc = (wave & 1) * (NT / 2);

    // A staging: two uint4/thread. row = tid>>2, k-planes (tid&3), (tid&3)+4.
    const int ar = tid >> 2, ap = tid & 3;
    const u16* gA = Ah + aBase + (long long)(bm + ar) * lda + ap * 8;

    // B staging: NT=128 -> four uint4/thread; NT=64 -> two.
    const int sm = tid >> 1, kh = (tid & 1) * 16, c0 = kh >> 3;   // NT=128
    const int br = tid >> 2, bp = tid & 3;                        // NT=64
    const u16* gB = (NT == 128)
        ? Bh + bBase + (long long)(bn + sm) * ldb + kh
        : Bh + bBase + (long long)(bn + br) * ldb + bp * 8;

    f32x4 acc[2][NJ];
#pragma unroll
    for (int i = 0; i < 2; i++)
#pragma unroll
        for (int j = 0; j < NJ; j++) {
            acc[i][j][0] = 0.f; acc[i][j][1] = 0.f;
            acc[i][j][2] = 0.f; acc[i][j][3] = 0.f;
        }

    for (int k0 = 0; k0 < K; k0 += 64) {
        uint4 a0 = *(const uint4*)(gA + k0);
        uint4 a1 = *(const uint4*)(gA + k0 + 32);
        uint4 b0, b1, b2, b3;
        b0 = *(const uint4*)(gB + k0);
        b2 = *(const uint4*)(gB + k0 + 32);
        if (NT == 128) {
            b1 = *(const uint4*)(gB + k0 + 8);
            b3 = *(const uint4*)(gB + k0 + 40);
        }
        __syncthreads();
        *(uint4*)&AhL[ap][ar][0]     = a0;
        *(uint4*)&AhL[ap + 4][ar][0] = a1;
        if (NT == 128) {
            *(uint4*)&BhL[c0][sm][0]     = b0;
            *(uint4*)&BhL[c0 + 1][sm][0] = b1;
            *(uint4*)&BhL[c0 + 4][sm][0] = b2;
            *(uint4*)&BhL[c0 + 5][sm][0] = b3;
        } else {
            *(uint4*)&BhL[bp][br][0]     = b0;
            *(uint4*)&BhL[bp + 4][br][0] = b2;
        }
        __syncthreads();

#pragma unroll
        for (int s = 0; s < 2; s++) {
            bf16x8 fah[2], fbh[NJ];
#pragma unroll
            for (int i = 0; i < 2; i++)
                fah[i] = *(const bf16x8*)&AhL[s * 4 + quad][wr + i * 16 + l16][0];
#pragma unroll
            for (int j = 0; j < NJ; j++)
                fbh[j] = *(const bf16x8*)&BhL[s * 4 + quad][wc + j * 16 + l16][0];
#pragma unroll
            for (int i = 0; i < 2; i++)
#pragma unroll
                for (int j = 0; j < NJ; j++)
                    acc[i][j] = __builtin_amdgcn_mfma_f32_16x16x32_bf16(fah[i], fbh[j], acc[i][j], 0, 0, 0);
        }
    }

    // ---- optional fused expmap0 (q/k slices of the qkv projection) ----
    if (NT == 128 && doExp && zp < 2) {
        const float qs = (zp == 0) ? QSCALE_L2E : 1.0f;
#pragma unroll
        for (int i = 0; i < 2; i++)
#pragma unroll
            for (int rr = 0; rr < 4; rr++) {
                float ps = 0.f;
#pragma unroll
                for (int j = 0; j < NJ; j++) {
                    float v = acc[i][j][rr];
                    ps += v * v;
                }
                ps += __shfl_xor(ps, 1, 64); ps += __shfl_xor(ps, 2, 64);
                ps += __shfl_xor(ps, 4, 64); ps += __shfl_xor(ps, 8, 64);
                if (l16 == 0) rsum[wr + i * 16 + quad * 4 + rr][wc >> 6] = ps;
            }
        __syncthreads();
#pragma unroll
        for (int i = 0; i < 2; i++)
#pragma unroll
            for (int rr = 0; rr < 4; rr++) {
                int m = wr + i * 16 + quad * 4 + rr;
                float n2 = rsum[m][0] + rsum[m][1];
                float nn = fmaxf(sqrtf(n2), 1e-6f);
                float e2 = exp2f(TWO_L2E * nn);          // e^{2n}
                float scl = (1.f - 2.f / (e2 + 1.f)) / nn * qs;  // tanh(n)/n * qs
#pragma unroll
                for (int j = 0; j < NJ; j++) acc[i][j][rr] *= scl;
            }
    }

#pragma unroll
    for (int i = 0; i < 2; i++)
#pragma unroll
        for (int j = 0; j < NJ; j++)
#pragma unroll
            for (int rr = 0; rr < 4; rr++) {
                int m = bm + wr + i * 16 + quad * 4 + rr;
                int n = bn + wc + j * 16 + l16;
                long long ci = cBase + (long long)m * ldc + n;
                float c = acc[i][j][rr] * alpha;
                if (accum) c += bf16f(Ch[ci]) + bf16f(Cl[ci]);
                u16 hh = bf16_rne(c);
                Ch[ci] = hh;
                if (storeL) Cl[ci] = bf16_rne(c - bf16f(hh));
            }
}

// ---------------------------------------------------------------------------
// Flash split-K partial, no-max softmax (bounded logits; Q pre-scaled by
// SCALE*log2e so P = exp2(sacc)). Emits unnormalized O_p (bf16) + l_p.
// R23 structure: QBLK=64, K/V via global_load_lds w16 + pre-swizzled src,
// 40960B LDS (4 blocks/CU), grid 1024. Proven best (R24's QBLK=128 cut
// co-residency and regressed).
// ---------------------------------------------------------------------------
__global__ __launch_bounds__(256) void flash_part(
    const u16* __restrict__ Qh, const u16* __restrict__ Kh,
    const u16* __restrict__ Vth,
    u16* __restrict__ Opart, float* __restrict__ Lpart)
{
    __shared__ __align__(16) u16 Kls[64 * 128];   // [key 64][d 128], swizzled
    __shared__ __align__(16) u16 Vls[128 * 64];   // [d 128][key 64], swizzled
    __shared__ __align__(16) u16 pls[64 * 64];    // [qrow 64][key 64], swizzled

    const int tid  = threadIdx.x;
    const int lane = tid & 63;
    const int w    = tid >> 6;
    const int quad = lane >> 4;
    const int l16  = lane & 15;
    const int z    = blockIdx.z;
    const int part = blockIdx.y;
    const int q0   = blockIdx.x * 64;
    const long long zoff = (long long)z * SDIM * DDIM;
    const int pz = part * NZ + z;
    const int sw = (l16 & 7) << 4;                // read-side swizzle (row&7)==(l16&7)

    // ---- global_load_lds staging geometry (pre-swizzled global source) ----
    const u16* kgp[4];
    const u16* vgp[4];
#pragma unroll
    for (int i = 0; i < 4; i++) {
        int rk = w * 16 + i * 4 + (lane >> 4);
        int sk = (lane & 15) ^ (rk & 7);
        kgp[i] = Kh + zoff + (long long)(part * 256 + rk) * DDIM + sk * 8;
        int rv = w * 32 + i * 8 + (lane >> 3);
        int sv = (lane & 7) ^ (rv & 7);
        vgp[i] = Vth + zoff + (long long)rv * SDIM + part * 256 + sv * 8;
    }

    const u16* qr = Qh + zoff + (long long)(q0 + w * 16 + l16) * DDIM;
    bf16x8 qf[4];
#pragma unroll
    for (int s = 0; s < 4; s++) qf[s] = *(const bf16x8*)(qr + s * 32 + quad * 8);

    f32x4 oacc[8];
#pragma unroll
    for (int dt = 0; dt < 8; dt++) {
        oacc[dt][0] = 0.f; oacc[dt][1] = 0.f; oacc[dt][2] = 0.f; oacc[dt][3] = 0.f;
    }
    float lp[4] = { 0.f, 0.f, 0.f, 0.f };

    for (int ti = 0; ti < 4; ti++) {
        __syncthreads();                          // prior compute done reading LDS
#pragma unroll
        for (int i = 0; i < 4; i++) {
            __builtin_amdgcn_global_load_lds(
                (glob_u8*)kgp[i], (lds_u8*)&Kls[w * 2048 + i * 512], 16, 0, 0);
            __builtin_amdgcn_global_load_lds(
                (glob_u8*)vgp[i], (lds_u8*)&Vls[w * 2048 + i * 512], 16, 0, 0);
            kgp[i] += 64 * DDIM;                  // next key-tile (K rows)
            vgp[i] += 64;                         // next key-tile (V cols)
        }
        __syncthreads();                          // vmcnt(0) drained -> tiles visible

        // ---- QK^T ----
        f32x4 sacc[4];
        __builtin_amdgcn_s_setprio(1);
#pragma unroll
        for (int ct = 0; ct < 4; ct++) {
            f32x4 a; a[0] = 0.f; a[1] = 0.f; a[2] = 0.f; a[3] = 0.f;
            const char* kb_row = (const char*)Kls + (ct * 16 + l16) * 256;
#pragma unroll
            for (int s = 0; s < 4; s++) {
                bf16x8 kb = *(const bf16x8*)(kb_row + (((s * 64) | (quad * 16)) ^ sw));
                a = __builtin_amdgcn_mfma_f32_16x16x32_bf16(qf[s], kb, a, 0, 0, 0);
            }
            sacc[ct] = a;
        }
        __builtin_amdgcn_s_setprio(0);

        // P = exp2(sacc); accumulate per-thread row partials (no max needed)
#pragma unroll
        for (int ct = 0; ct < 4; ct++)
#pragma unroll
            for (int r = 0; r < 4; r++) {
                float p = exp2f(sacc[ct][r]);
                lp[r] += p;
                int prow = w * 16 + quad * 4 + r;
                int pcol = ct * 16 + l16;
                *(u16*)((char*)pls + prow * 128 + ((pcol * 2) ^ ((prow & 7) << 4))) = bf16_rne(p);
            }

        bf16x8 pa[2];
        {
            const char* p_row = (const char*)pls + (w * 16 + l16) * 128;
#pragma unroll
            for (int ks2 = 0; ks2 < 2; ks2++)
                pa[ks2] = *(const bf16x8*)(p_row + (((ks2 * 64) | (quad * 16)) ^ sw));
        }

        // ---- PV ----
        __builtin_amdgcn_s_setprio(1);
#pragma unroll
        for (int dt = 0; dt < 8; dt++) {
            f32x4 o = oacc[dt];
            const char* v_row = (const char*)Vls + (dt * 16 + l16) * 128;
#pragma unroll
            for (int ks2 = 0; ks2 < 2; ks2++) {
                bf16x8 vb = *(const bf16x8*)(v_row + (((ks2 * 64) | (quad * 16)) ^ sw));
                o = __builtin_amdgcn_mfma_f32_16x16x32_bf16(pa[ks2], vb, o, 0, 0, 0);
            }
            oacc[dt] = o;
        }
        __builtin_amdgcn_s_setprio(0);
    }

    const long long obase = (long long)pz * SDIM * DDIM;
#pragma unroll
    for (int dt = 0; dt < 8; dt++)
#pragma unroll
        for (int r = 0; r < 4; r++) {
            int srow = q0 + w * 16 + quad * 4 + r;
            Opart[obase + (long long)srow * DDIM + dt * 16 + l16] = bf16_rne(oacc[dt][r]);
        }
#pragma unroll
    for (int r = 0; r < 4; r++) {
        float s = lp[r];
        s += __shfl_xor(s, 1, 64); s += __shfl_xor(s, 2, 64);
        s += __shfl_xor(s, 4, 64); s += __shfl_xor(s, 8, 64);
        if (l16 == 0) {
            int srow = q0 + w * 16 + quad * 4 + r;
            Lpart[(long long)pz * SDIM + srow] = s;
        }
    }
}

// ---------------------------------------------------------------------------
// Combine: O = sum_p O_p / sum_p l_p. Vectorized: 8 elem/thread (bf16x8).
// grid 1024 x 256 thr; thread i -> row i/16, d-slice (i%16)*8.
// ---------------------------------------------------------------------------
__global__ __launch_bounds__(256) void flash_combine(
    const u16* __restrict__ Opart, const float* __restrict__ Lpart,
    u16* __restrict__ Oh)
{
    const long long i = (long long)blockIdx.x * 256 + threadIdx.x;  // 0..262143
    const int rg = (int)(i >> 4);                 // 0..16383 = z*1024+row
    const int z = rg >> 10, row = rg & 1023;
    const int d0 = ((int)i & 15) * 8;
    float lt = 0.f;
#pragma unroll
    for (int p = 0; p < NPART; p++)
        lt += Lpart[(long long)(p * NZ + z) * SDIM + row];
    const float inv = 1.f / lt;
    float o[8] = { 0.f, 0.f, 0.f, 0.f, 0.f, 0.f, 0.f, 0.f };
#pragma unroll
    for (int p = 0; p < NPART; p++) {
        bf16x8 v = *(const bf16x8*)&Opart[
            (long long)(p * NZ + z) * SDIM * DDIM + (long long)row * DDIM + d0];
#pragma unroll
        for (int j = 0; j < 8; j++) o[j] += bf16f((u16)v[j]);
    }
    unsigned w4[4];
#pragma unroll
    for (int j = 0; j < 4; j++)
        w4[j] = (unsigned)bf16_rne(o[2 * j] * inv)
              | ((unsigned)bf16_rne(o[2 * j + 1] * inv) << 16);
    const int b = z >> 3, h = z & 7;
    *(uint4*)&Oh[(long long)b * SDIM * EDIM + (long long)row * EDIM + h * DDIM + d0] =
        make_uint4(w4[0], w4[1], w4[2], w4[3]);
}

// ---------------------------------------------------------------------------
// Generic 64x64-tile transpose. grid (rT, cT, nz).
// ---------------------------------------------------------------------------
__global__ __launch_bounds__(256) void transpose_g(
    const u16* __restrict__ src, u16* __restrict__ dst,
    int ldS, int ldD, long long sZ, long long dZ)
{
    __shared__ __align__(16) u16 tl[64][72];
    const int r0 = blockIdx.x * 64, c0 = blockIdx.y * 64;
    const u16* s = src + (long long)blockIdx.z * sZ;
    u16* d = dst + (long long)blockIdx.z * dZ;
    const int t = threadIdx.x;
    const int sr = t >> 2, dc = (t & 3) * 16;
    {
        const u16* p = s + (long long)(r0 + sr) * ldS + c0 + dc;
        *(uint4*)&tl[sr][dc]     = *(const uint4*)p;
        *(uint4*)&tl[sr][dc + 8] = *(const uint4*)(p + 8);
    }
    __syncthreads();
    const int dr = t >> 2, sc = (t & 3) * 16;
    unsigned wbuf[8];
#pragma unroll
    for (int i = 0; i < 8; i++)
        wbuf[i] = (unsigned)tl[sc + 2 * i][dr] | ((unsigned)tl[sc + 2 * i + 1][dr] << 16);
    u16* po = d + (long long)(c0 + dr) * ldD + r0 + sc;
    *(uint4*)po = make_uint4(wbuf[0], wbuf[1], wbuf[2], wbuf[3]);
    *(uint4*)(po + 8) = make_uint4(wbuf[4], wbuf[5], wbuf[6], wbuf[7]);
}

// final output: f32 = h + l (zero-fill past nmax)
__global__ __launch_bounds__(256) void out_k(
    const u16* __restrict__ h, const u16* __restrict__ l,
    float* __restrict__ out, long long n, long long nmax)
{
    long long i = (long long)blockIdx.x * 256 + threadIdx.x;
    if (i < n) out[i] = (i < nmax) ? (bf16f(h[i]) + bf16f(l[i])) : 0.f;
}

#define N2   2097152LL            // B*S*E == NZ*S*D
#define W3N  3145728LL            // 3E*E
#define WON  1048576LL            // E*E
#define WHN  49152LL              // 3*D*D
#define EE   1048576LL            // E*E

extern "C" void kernel_launch(void* const* d_in, const int* in_sizes, int n_in,
                              void* d_out, int out_size, void* d_ws, size_t ws_size,
                              hipStream_t stream)
{
    const float* x       = (const float*)d_in[0];
    const float* Wqkv    = (const float*)d_in[1];
    const float* Wq      = (const float*)d_in[3];
    const float* Wk      = (const float*)d_in[5];
    const float* Wv      = (const float*)d_in[7];
    const float* Wout    = (const float*)d_in[9];
    const float* Wlayers = (const float*)d_in[11];

    u16* ws = (u16*)d_ws;
    long long o = 0;
    u16 *curh = ws + o; o += N2;  u16 *curl = ws + o; o += N2;
    u16 *qkvh = ws + o; o += 3 * N2;
    u16 *vth  = ws + o; o += N2;
    u16 *aoh  = ws + o; o += N2;
    u16 *wqh  = ws + o; o += W3N;
    u16 *wqth = ws + o; o += W3N;
    u16 *wfh  = ws + o; o += W3N;
    u16 *whh  = ws + o; o += WHN;
    u16 *woh  = ws + o; o += WON;
    u16 *woth = ws + o; o += WON;
    u16 *wlh  = ws + o; o += W3N;
    u16 *wloh = ws + o; o += W3N;
    u16 *Opart = ws + o; o += NPART * NZ * SDIM * DDIM;          // bf16
    float *Lpart = (float*)(ws + o); o += 2 * NPART * NZ * SDIM;
    // total < 184 MB

    // ---- one-time: splits (weights: h-plane only) ----
    split_k<<<2048, 256, 0, stream>>>(x, curh, curl, N2 / 4);
    splith_k<<<3072, 256, 0, stream>>>(Wqkv, wqh, W3N / 4);
    split3_k<<<48, 256, 0, stream>>>(Wq, Wk, Wv, whh);
    splith_k<<<1024, 256, 0, stream>>>(Wout, woh, WON / 4);
    splith_k<<<3072, 256, 0, stream>>>(Wlayers, wlh, W3N / 4);

    // ---- one-time: transposes (h-planes only) ----
    transpose_g<<<dim3(48, 16, 1), 256, 0, stream>>>(wqh, wqth, EDIM, 3 * EDIM, 0, 0);
    transpose_g<<<dim3(16, 16, 1), 256, 0, stream>>>(woh, woth, EDIM, EDIM, 0, 0);

    // ---- one-time: Wfused = blockdiag(Wq,Wk,Wv) @ Wqkv  (single-bf16) ----
    gemm_t<128><<<dim3(8, 2, 24), 256, 0, stream>>>(
        whh, 0, DDIM, (long long)DDIM * DDIM, 0, 0,
        wqth, 0, 3 * EDIM, EDIM, 0, DDIM,
        wfh, wfh, 0, EDIM, (long long)EDIM * EDIM, 0, (long long)DDIM * EDIM,
        1, 8, DDIM, 1.0f, 0, 0, 0);

    // ---- one-time: Wlo[l] = Wlayers[l] @ Wout  (single-bf16) ----
    gemm_t<64><<<dim3(16, 16, 3), 256, 0, stream>>>(
        wlh, 0, EDIM, EE, 0, 0,
        woth, 0, EDIM, 0, 0, 0,
        wloh, wloh, 0, EDIM, EE, 0, 0,
        1, 1, EDIM, 1.0f, 0, 0, 0);

    for (int layer = 0; layer < LNUM; layer++) {
        // qkv fused + epilogue expmap (q scaled by SCALE*log2e):
        // z = p*16 + b*8 + h: M=1024(s), N=128(d), K=1024
        gemm_t<128><<<dim3(1, 16, 48), 256, 0, stream>>>(
            curh, 0, EDIM, 0, (long long)SDIM * EDIM, 0,
            wfh, 0, EDIM, EE, 0, (long long)DDIM * EDIM,
            qkvh, qkvh, 0, DDIM, N2, (long long)HDIM * SDIM * DDIM, (long long)SDIM * DDIM,
            2, 8, EDIM, 1.0f, 0, 0, 1);

        // Vt[z][D][S] = V[z]^T
        transpose_g<<<dim3(16, 2, NZ), 256, 0, stream>>>(
            qkvh + 2 * N2, vth, DDIM, SDIM, (long long)SDIM * DDIM, (long long)SDIM * DDIM);

        // flash split-K partials + combine -> attnout (h only)
        flash_part<<<dim3(16, NPART, NZ), 256, 0, stream>>>(
            qkvh, qkvh + N2, vth, Opart, Lpart);
        flash_combine<<<1024, 256, 0, stream>>>(Opart, Lpart, aoh);

        // cur += attnout @ Wlo[layer]^T
        gemm_t<64><<<dim3(16, 32, 1), 256, 0, stream>>>(
            aoh, 0, EDIM, 0, 0, 0,
            wloh, (long long)layer * EE, EDIM, 0, 0, 0,
            curh, curl, 0, EDIM, 0, 0, 0,
            1, 1, EDIM, 1.0f, 1, 1, 0);
    }

    out_k<<<(out_size + 255) / 256, 256, 0, stream>>>(
        curh, curl, (float*)d_out, out_size, N2);
}

// Round 14
// 366.541 us; speedup vs baseline: 1.0983x; 1.0282x over previous
//
#include <hip/hip_runtime.h>
#include <math.h>

// Problem constants (reference: B=2,S=1024,E=1024,H=8,D=128,L=3)
#define BDIM 2
#define SDIM 1024
#define EDIM 1024
#define HDIM 8
#define DDIM 128
#define LNUM 3
#define NZ 16
#define NPART 4
#define SCALE_F 0.08838834764831845f
#define QSCALE_L2E 0.12751742f     // SCALE * log2(e)
#define TWO_L2E 2.8853901f         // 2 * log2(e)

// WORLD MODEL (verified R6-R11): complex64 lowered to f32 REAL-PART-ONLY.
// Precision: residual `cur` bf16x3 (h+l); everything else single bf16.
// R12: no-max softmax + exp2; weight folds; expmap fused in qkv epilogue.
// R13/R14 (REGRESSED): cross-barrier reg prefetch (32 VGPR) spilled.
// R15 (WIN, 477): flash K/V via global_load_lds w16 + pre-swizzled source.
// R16/R17 (WIN, 422.8): 64-row gemm tiles double block count.
// R18/R19 (REG/NEUTRAL, 457): gload_lds in gemm loses to reg-staging.
// R20 (WIN, 404.7): reg-staged gemm; Opart bf16 banked.
// R21 (WIN, 377.9): BK 32->64 halves per-block barrier/drain count.
// R22 (SEVERE REG, 696.8): BK=128 staging spilled. BK=64 final.
// R23 (OK, 383.4): revert confirmed; h-only splits banked.
// R24 (REG, 402.6): flash QBLK=128 cut co-residency 4->2 blocks/CU.
// Lesson: flash needs 4 blocks/CU (no in-block ILP); gemm is opposite.
// R25 (WIN, 376.9): flash QBLK=64 restored; vectorized combine banked.
// R26: fuse V-transpose into qkv gemm epilogue (TR=1): zp==2 blocks write
// Vt[d][s] directly via 128x72 LDS shuffle + coalesced stores (bit-identical
// values; per-layer transpose_g launch + 8MB traffic removed). LDS 43KB,
// 3 blocks/CU = grid. qkvh V region now dead.

typedef unsigned short u16;
typedef __attribute__((ext_vector_type(8))) short bf16x8;
typedef __attribute__((ext_vector_type(4))) float f32x4;
typedef __attribute__((address_space(3))) unsigned char lds_u8;
typedef __attribute__((address_space(1))) const unsigned char glob_u8;

__device__ __forceinline__ u16 bf16_rne(float x) {
    unsigned u = __float_as_uint(x);
    u += 0x7FFFu + ((u >> 16) & 1u);
    return (u16)(u >> 16);
}
__device__ __forceinline__ float bf16f(u16 h) {
    return __uint_as_float(((unsigned)h) << 16);
}

// ---------------------------------------------------------------------------
__global__ __launch_bounds__(256) void split_k(
    const float* __restrict__ in, u16* __restrict__ h, u16* __restrict__ l,
    long long n4)
{
    long long i = (long long)blockIdx.x * 256 + threadIdx.x;
    if (i >= n4) return;
    float4 v = ((const float4*)in)[i];
    float vv[4] = { v.x, v.y, v.z, v.w };
    u16 hh[4], ll[4];
#pragma unroll
    for (int j = 0; j < 4; j++) {
        hh[j] = bf16_rne(vv[j]);
        ll[j] = bf16_rne(vv[j] - bf16f(hh[j]));
    }
    ((uint2*)h)[i] = make_uint2((unsigned)hh[0] | ((unsigned)hh[1] << 16),
                                (unsigned)hh[2] | ((unsigned)hh[3] << 16));
    ((uint2*)l)[i] = make_uint2((unsigned)ll[0] | ((unsigned)ll[1] << 16),
                                (unsigned)ll[2] | ((unsigned)ll[3] << 16));
}

// h-plane-only split (weights: l-plane is discarded anyway).
__global__ __launch_bounds__(256) void splith_k(
    const float* __restrict__ in, u16* __restrict__ h, long long n4)
{
    long long i = (long long)blockIdx.x * 256 + threadIdx.x;
    if (i >= n4) return;
    float4 v = ((const float4*)in)[i];
    ((uint2*)h)[i] = make_uint2(
        (unsigned)bf16_rne(v.x) | ((unsigned)bf16_rne(v.y) << 16),
        (unsigned)bf16_rne(v.z) | ((unsigned)bf16_rne(v.w) << 16));
}

// Batched split for the three DxD head weights (h-plane only). 48 blocks.
__global__ __launch_bounds__(256) void split3_k(
    const float* __restrict__ a, const float* __restrict__ b,
    const float* __restrict__ c, u16* __restrict__ h)
{
    const int t = blockIdx.x >> 4;                 // 0..2
    const float* src = (t == 0) ? a : (t == 1) ? b : c;
    const long long i = (long long)(blockIdx.x & 15) * 256 + threadIdx.x; // [0,4096)
    float4 v = ((const float4*)src)[i];
    u16* hp = h + (long long)t * 16384;
    ((uint2*)hp)[i] = make_uint2(
        (unsigned)bf16_rne(v.x) | ((unsigned)bf16_rne(v.y) << 16),
        (unsigned)bf16_rne(v.z) | ((unsigned)bf16_rne(v.w) << 16));
}

// ---------------------------------------------------------------------------
// Single-bf16 GEMM, tile 64 x NT x 64 (BK=64, R21 proven), 256 thr (4 waves
// 2x2), acc[2][NT/32]. Reg-staged same-iteration staging.
// C[m,n] = alpha*sum_k A[m,k]*B[n,k] (+Ch+Cl if accum). storeL: write l-plane.
// doExp (NT==128 only): zp==0/1 -> expmap0 per output row in-epilogue.
// TR (NT==128 only): zp==2 blocks write output TRANSPOSED to Vt[d][s]
// (requires bn==0, N==128 == full d row) via LDS shuffle; normal C-write
// skipped for those blocks. K must be a multiple of 64.
// ---------------------------------------------------------------------------
template<int NT, int TR>
__global__ __launch_bounds__(256) void gemm_t(
    const u16* __restrict__ Ah,
    long long aOff, int lda, long long aSP, long long aSB, long long aSH,
    const u16* __restrict__ Bh,
    long long bOff, int ldb, long long bSP, long long bSB, long long bSH,
    u16* __restrict__ Ch, u16* __restrict__ Cl, u16* __restrict__ Vt,
    long long cOff, int ldc, long long cSP, long long cSB, long long cSH,
    int Bdec, int Hdec, int K, float alpha, int accum, int storeL, int doExp)
{
    constexpr int NJ = NT / 32;                   // j-tiles per wave
    __shared__ __align__(16) u16 AhL[8][64][8];   // kp 0..7
    __shared__ __align__(16) u16 BhL[8][NT][8];
    __shared__ float rsum[64][2];
    __shared__ __align__(16) u16 tl[TR ? 128 * 72 : 16];  // transpose staging

    const int tid  = threadIdx.x;
    const int lane = tid & 63;
    const int wave = tid >> 6;
    const int quad = lane >> 4;
    const int l16  = lane & 15;
    const int z  = blockIdx.z;
    const int zp = z / (Bdec * Hdec);
    const int r  = z - zp * Bdec * Hdec;
    const int zb = r / Hdec, zh = r - zb * Hdec;
    const long long aBase = aOff + (long long)zp * aSP + (long long)zb * aSB + (long long)zh * aSH;
    const long long bBase = bOff + (long long)zp * bSP + (long long)zb * bSB + (long long)zh * bSH;
    const long long cBase = cOff + (long long)zp * cSP + (long long)zb * cSB + (long long)zh * cSH;
    const int bm = blockIdx.y * 64, bn = blockIdx.x * NT;
    const int wr = (wave >> 1) * 32, wc = (wave & 1) * (NT / 2);

    // A staging: two uint4/thread. row = tid>>2, k-planes (tid&3), (tid&3)+4.
    const int ar = tid >> 2, ap = tid & 3;
    const u16* gA = Ah + aBase + (long long)(bm + ar) * lda + ap * 8;

    // B staging: NT=128 -> four uint4/thread; NT=64 -> two.
    const int sm = tid >> 1, kh = (tid & 1) * 16, c0 = kh >> 3;   // NT=128
    const int br = tid >> 2, bp = tid & 3;                        // NT=64
    const u16* gB = (NT == 128)
        ? Bh + bBase + (long long)(bn + sm) * ldb + kh
        : Bh + bBase + (long long)(bn + br) * ldb + bp * 8;

    f32x4 acc[2][NJ];
#pragma unroll
    for (int i = 0; i < 2; i++)
#pragma unroll
        for (int j = 0; j < NJ; j++) {
            acc[i][j][0] = 0.f; acc[i][j][1] = 0.f;
            acc[i][j][2] = 0.f; acc[i][j][3] = 0.f;
        }

    for (int k0 = 0; k0 < K; k0 += 64) {
        uint4 a0 = *(const uint4*)(gA + k0);
        uint4 a1 = *(const uint4*)(gA + k0 + 32);
        uint4 b0, b1, b2, b3;
        b0 = *(const uint4*)(gB + k0);
        b2 = *(const uint4*)(gB + k0 + 32);
        if (NT == 128) {
            b1 = *(const uint4*)(gB + k0 + 8);
            b3 = *(const uint4*)(gB + k0 + 40);
        }
        __syncthreads();
        *(uint4*)&AhL[ap][ar][0]     = a0;
        *(uint4*)&AhL[ap + 4][ar][0] = a1;
        if (NT == 128) {
            *(uint4*)&BhL[c0][sm][0]     = b0;
            *(uint4*)&BhL[c0 + 1][sm][0] = b1;
            *(uint4*)&BhL[c0 + 4][sm][0] = b2;
            *(uint4*)&BhL[c0 + 5][sm][0] = b3;
        } else {
            *(uint4*)&BhL[bp][br][0]     = b0;
            *(uint4*)&BhL[bp + 4][br][0] = b2;
        }
        __syncthreads();

#pragma unroll
        for (int s = 0; s < 2; s++) {
            bf16x8 fah[2], fbh[NJ];
#pragma unroll
            for (int i = 0; i < 2; i++)
                fah[i] = *(const bf16x8*)&AhL[s * 4 + quad][wr + i * 16 + l16][0];
#pragma unroll
            for (int j = 0; j < NJ; j++)
                fbh[j] = *(const bf16x8*)&BhL[s * 4 + quad][wc + j * 16 + l16][0];
#pragma unroll
            for (int i = 0; i < 2; i++)
#pragma unroll
                for (int j = 0; j < NJ; j++)
                    acc[i][j] = __builtin_amdgcn_mfma_f32_16x16x32_bf16(fah[i], fbh[j], acc[i][j], 0, 0, 0);
        }
    }

    // ---- TR path: zp==2 (V slice) -> write transposed Vt[d][s] ----
    if (TR && zp == 2) {
#pragma unroll
        for (int i = 0; i < 2; i++)
#pragma unroll
            for (int j = 0; j < NJ; j++)
#pragma unroll
                for (int rr = 0; rr < 4; rr++) {
                    int ml = wr + i * 16 + quad * 4 + rr;   // s (0..63)
                    int nl = wc + j * 16 + l16;             // d (0..127)
                    tl[nl * 72 + ml] = bf16_rne(acc[i][j][rr] * alpha);
                }
        __syncthreads();
        const long long vtBase = ((long long)zb * 8 + zh) * SDIM * DDIM;
        const int rn = tid >> 1, ms = (tid & 1) * 32;
        u16* po = Vt + vtBase + (long long)rn * SDIM + bm + ms;
        const u16* ps = &tl[rn * 72 + ms];
        *(uint4*)(po)      = *(const uint4*)(ps);
        *(uint4*)(po + 8)  = *(const uint4*)(ps + 8);
        *(uint4*)(po + 16) = *(const uint4*)(ps + 16);
        *(uint4*)(po + 24) = *(const uint4*)(ps + 24);
        return;
    }

    // ---- optional fused expmap0 (q/k slices of the qkv projection) ----
    if (NT == 128 && doExp && zp < 2) {
        const float qs = (zp == 0) ? QSCALE_L2E : 1.0f;
#pragma unroll
        for (int i = 0; i < 2; i++)
#pragma unroll
            for (int rr = 0; rr < 4; rr++) {
                float ps = 0.f;
#pragma unroll
                for (int j = 0; j < NJ; j++) {
                    float v = acc[i][j][rr];
                    ps += v * v;
                }
                ps += __shfl_xor(ps, 1, 64); ps += __shfl_xor(ps, 2, 64);
                ps += __shfl_xor(ps, 4, 64); ps += __shfl_xor(ps, 8, 64);
                if (l16 == 0) rsum[wr + i * 16 + quad * 4 + rr][wc >> 6] = ps;
            }
        __syncthreads();
#pragma unroll
        for (int i = 0; i < 2; i++)
#pragma unroll
            for (int rr = 0; rr < 4; rr++) {
                int m = wr + i * 16 + quad * 4 + rr;
                float n2 = rsum[m][0] + rsum[m][1];
                float nn = fmaxf(sqrtf(n2), 1e-6f);
                float e2 = exp2f(TWO_L2E * nn);          // e^{2n}
                float scl = (1.f - 2.f / (e2 + 1.f)) / nn * qs;  // tanh(n)/n * qs
#pragma unroll
                for (int j = 0; j < NJ; j++) acc[i][j][rr] *= scl;
            }
    }

#pragma unroll
    for (int i = 0; i < 2; i++)
#pragma unroll
        for (int j = 0; j < NJ; j++)
#pragma unroll
            for (int rr = 0; rr < 4; rr++) {
                int m = bm + wr + i * 16 + quad * 4 + rr;
                int n = bn + wc + j * 16 + l16;
                long long ci = cBase + (long long)m * ldc + n;
                float c = acc[i][j][rr] * alpha;
                if (accum) c += bf16f(Ch[ci]) + bf16f(Cl[ci]);
                u16 hh = bf16_rne(c);
                Ch[ci] = hh;
                if (storeL) Cl[ci] = bf16_rne(c - bf16f(hh));
            }
}

// ---------------------------------------------------------------------------
// Flash split-K partial, no-max softmax (bounded logits; Q pre-scaled by
// SCALE*log2e so P = exp2(sacc)). Emits unnormalized O_p (bf16) + l_p.
// R23 structure: QBLK=64, K/V via global_load_lds w16 + pre-swizzled src,
// 40960B LDS (4 blocks/CU), grid 1024.
// ---------------------------------------------------------------------------
__global__ __launch_bounds__(256) void flash_part(
    const u16* __restrict__ Qh, const u16* __restrict__ Kh,
    const u16* __restrict__ Vth,
    u16* __restrict__ Opart, float* __restrict__ Lpart)
{
    __shared__ __align__(16) u16 Kls[64 * 128];   // [key 64][d 128], swizzled
    __shared__ __align__(16) u16 Vls[128 * 64];   // [d 128][key 64], swizzled
    __shared__ __align__(16) u16 pls[64 * 64];    // [qrow 64][key 64], swizzled

    const int tid  = threadIdx.x;
    const int lane = tid & 63;
    const int w    = tid >> 6;
    const int quad = lane >> 4;
    const int l16  = lane & 15;
    const int z    = blockIdx.z;
    const int part = blockIdx.y;
    const int q0   = blockIdx.x * 64;
    const long long zoff = (long long)z * SDIM * DDIM;
    const int pz = part * NZ + z;
    const int sw = (l16 & 7) << 4;                // read-side swizzle (row&7)==(l16&7)

    // ---- global_load_lds staging geometry (pre-swizzled global source) ----
    const u16* kgp[4];
    const u16* vgp[4];
#pragma unroll
    for (int i = 0; i < 4; i++) {
        int rk = w * 16 + i * 4 + (lane >> 4);
        int sk = (lane & 15) ^ (rk & 7);
        kgp[i] = Kh + zoff + (long long)(part * 256 + rk) * DDIM + sk * 8;
        int rv = w * 32 + i * 8 + (lane >> 3);
        int sv = (lane & 7) ^ (rv & 7);
        vgp[i] = Vth + zoff + (long long)rv * SDIM + part * 256 + sv * 8;
    }

    const u16* qr = Qh + zoff + (long long)(q0 + w * 16 + l16) * DDIM;
    bf16x8 qf[4];
#pragma unroll
    for (int s = 0; s < 4; s++) qf[s] = *(const bf16x8*)(qr + s * 32 + quad * 8);

    f32x4 oacc[8];
#pragma unroll
    for (int dt = 0; dt < 8; dt++) {
        oacc[dt][0] = 0.f; oacc[dt][1] = 0.f; oacc[dt][2] = 0.f; oacc[dt][3] = 0.f;
    }
    float lp[4] = { 0.f, 0.f, 0.f, 0.f };

    for (int ti = 0; ti < 4; ti++) {
        __syncthreads();                          // prior compute done reading LDS
#pragma unroll
        for (int i = 0; i < 4; i++) {
            __builtin_amdgcn_global_load_lds(
                (glob_u8*)kgp[i], (lds_u8*)&Kls[w * 2048 + i * 512], 16, 0, 0);
            __builtin_amdgcn_global_load_lds(
                (glob_u8*)vgp[i], (lds_u8*)&Vls[w * 2048 + i * 512], 16, 0, 0);
            kgp[i] += 64 * DDIM;                  // next key-tile (K rows)
            vgp[i] += 64;                         // next key-tile (V cols)
        }
        __syncthreads();                          // vmcnt(0) drained -> tiles visible

        // ---- QK^T ----
        f32x4 sacc[4];
        __builtin_amdgcn_s_setprio(1);
#pragma unroll
        for (int ct = 0; ct < 4; ct++) {
            f32x4 a; a[0] = 0.f; a[1] = 0.f; a[2] = 0.f; a[3] = 0.f;
            const char* kb_row = (const char*)Kls + (ct * 16 + l16) * 256;
#pragma unroll
            for (int s = 0; s < 4; s++) {
                bf16x8 kb = *(const bf16x8*)(kb_row + (((s * 64) | (quad * 16)) ^ sw));
                a = __builtin_amdgcn_mfma_f32_16x16x32_bf16(qf[s], kb, a, 0, 0, 0);
            }
            sacc[ct] = a;
        }
        __builtin_amdgcn_s_setprio(0);

        // P = exp2(sacc); accumulate per-thread row partials (no max needed)
#pragma unroll
        for (int ct = 0; ct < 4; ct++)
#pragma unroll
            for (int r = 0; r < 4; r++) {
                float p = exp2f(sacc[ct][r]);
                lp[r] += p;
                int prow = w * 16 + quad * 4 + r;
                int pcol = ct * 16 + l16;
                *(u16*)((char*)pls + prow * 128 + ((pcol * 2) ^ ((prow & 7) << 4))) = bf16_rne(p);
            }

        bf16x8 pa[2];
        {
            const char* p_row = (const char*)pls + (w * 16 + l16) * 128;
#pragma unroll
            for (int ks2 = 0; ks2 < 2; ks2++)
                pa[ks2] = *(const bf16x8*)(p_row + (((ks2 * 64) | (quad * 16)) ^ sw));
        }

        // ---- PV ----
        __builtin_amdgcn_s_setprio(1);
#pragma unroll
        for (int dt = 0; dt < 8; dt++) {
            f32x4 o = oacc[dt];
            const char* v_row = (const char*)Vls + (dt * 16 + l16) * 128;
#pragma unroll
            for (int ks2 = 0; ks2 < 2; ks2++) {
                bf16x8 vb = *(const bf16x8*)(v_row + (((ks2 * 64) | (quad * 16)) ^ sw));
                o = __builtin_amdgcn_mfma_f32_16x16x32_bf16(pa[ks2], vb, o, 0, 0, 0);
            }
            oacc[dt] = o;
        }
        __builtin_amdgcn_s_setprio(0);
    }

    const long long obase = (long long)pz * SDIM * DDIM;
#pragma unroll
    for (int dt = 0; dt < 8; dt++)
#pragma unroll
        for (int r = 0; r < 4; r++) {
            int srow = q0 + w * 16 + quad * 4 + r;
            Opart[obase + (long long)srow * DDIM + dt * 16 + l16] = bf16_rne(oacc[dt][r]);
        }
#pragma unroll
    for (int r = 0; r < 4; r++) {
        float s = lp[r];
        s += __shfl_xor(s, 1, 64); s += __shfl_xor(s, 2, 64);
        s += __shfl_xor(s, 4, 64); s += __shfl_xor(s, 8, 64);
        if (l16 == 0) {
            int srow = q0 + w * 16 + quad * 4 + r;
            Lpart[(long long)pz * SDIM + srow] = s;
        }
    }
}

// ---------------------------------------------------------------------------
// Combine: O = sum_p O_p / sum_p l_p. Vectorized: 8 elem/thread (bf16x8).
// grid 1024 x 256 thr; thread i -> row i/16, d-slice (i%16)*8.
// ---------------------------------------------------------------------------
__global__ __launch_bounds__(256) void flash_combine(
    const u16* __restrict__ Opart, const float* __restrict__ Lpart,
    u16* __restrict__ Oh)
{
    const long long i = (long long)blockIdx.x * 256 + threadIdx.x;  // 0..262143
    const int rg = (int)(i >> 4);                 // 0..16383 = z*1024+row
    const int z = rg >> 10, row = rg & 1023;
    const int d0 = ((int)i & 15) * 8;
    float lt = 0.f;
#pragma unroll
    for (int p = 0; p < NPART; p++)
        lt += Lpart[(long long)(p * NZ + z) * SDIM + row];
    const float inv = 1.f / lt;
    float o[8] = { 0.f, 0.f, 0.f, 0.f, 0.f, 0.f, 0.f, 0.f };
#pragma unroll
    for (int p = 0; p < NPART; p++) {
        bf16x8 v = *(const bf16x8*)&Opart[
            (long long)(p * NZ + z) * SDIM * DDIM + (long long)row * DDIM + d0];
#pragma unroll
        for (int j = 0; j < 8; j++) o[j] += bf16f((u16)v[j]);
    }
    unsigned w4[4];
#pragma unroll
    for (int j = 0; j < 4; j++)
        w4[j] = (unsigned)bf16_rne(o[2 * j] * inv)
              | ((unsigned)bf16_rne(o[2 * j + 1] * inv) << 16);
    const int b = z >> 3, h = z & 7;
    *(uint4*)&Oh[(long long)b * SDIM * EDIM + (long long)row * EDIM + h * DDIM + d0] =
        make_uint4(w4[0], w4[1], w4[2], w4[3]);
}

// ---------------------------------------------------------------------------
// Generic 64x64-tile transpose. grid (rT, cT, nz).  (one-time weights only)
// ---------------------------------------------------------------------------
__global__ __launch_bounds__(256) void transpose_g(
    const u16* __restrict__ src, u16* __restrict__ dst,
    int ldS, int ldD, long long sZ, long long dZ)
{
    __shared__ __align__(16) u16 tl[64][72];
    const int r0 = blockIdx.x * 64, c0 = blockIdx.y * 64;
    const u16* s = src + (long long)blockIdx.z * sZ;
    u16* d = dst + (long long)blockIdx.z * dZ;
    const int t = threadIdx.x;
    const int sr = t >> 2, dc = (t & 3) * 16;
    {
        const u16* p = s + (long long)(r0 + sr) * ldS + c0 + dc;
        *(uint4*)&tl[sr][dc]     = *(const uint4*)p;
        *(uint4*)&tl[sr][dc + 8] = *(const uint4*)(p + 8);
    }
    __syncthreads();
    const int dr = t >> 2, sc = (t & 3) * 16;
    unsigned wbuf[8];
#pragma unroll
    for (int i = 0; i < 8; i++)
        wbuf[i] = (unsigned)tl[sc + 2 * i][dr] | ((unsigned)tl[sc + 2 * i + 1][dr] << 16);
    u16* po = d + (long long)(c0 + dr) * ldD + r0 + sc;
    *(uint4*)po = make_uint4(wbuf[0], wbuf[1], wbuf[2], wbuf[3]);
    *(uint4*)(po + 8) = make_uint4(wbuf[4], wbuf[5], wbuf[6], wbuf[7]);
}

// final output: f32 = h + l (zero-fill past nmax)
__global__ __launch_bounds__(256) void out_k(
    const u16* __restrict__ h, const u16* __restrict__ l,
    float* __restrict__ out, long long n, long long nmax)
{
    long long i = (long long)blockIdx.x * 256 + threadIdx.x;
    if (i < n) out[i] = (i < nmax) ? (bf16f(h[i]) + bf16f(l[i])) : 0.f;
}

#define N2   2097152LL            // B*S*E == NZ*S*D
#define W3N  3145728LL            // 3E*E
#define WON  1048576LL            // E*E
#define WHN  49152LL              // 3*D*D
#define EE   1048576LL            // E*E

extern "C" void kernel_launch(void* const* d_in, const int* in_sizes, int n_in,
                              void* d_out, int out_size, void* d_ws, size_t ws_size,
                              hipStream_t stream)
{
    const float* x       = (const float*)d_in[0];
    const float* Wqkv    = (const float*)d_in[1];
    const float* Wq      = (const float*)d_in[3];
    const float* Wk      = (const float*)d_in[5];
    const float* Wv      = (const float*)d_in[7];
    const float* Wout    = (const float*)d_in[9];
    const float* Wlayers = (const float*)d_in[11];

    u16* ws = (u16*)d_ws;
    long long o = 0;
    u16 *curh = ws + o; o += N2;  u16 *curl = ws + o; o += N2;
    u16 *qkvh = ws + o; o += 3 * N2;
    u16 *vth  = ws + o; o += N2;
    u16 *aoh  = ws + o; o += N2;
    u16 *wqh  = ws + o; o += W3N;
    u16 *wqth = ws + o; o += W3N;
    u16 *wfh  = ws + o; o += W3N;
    u16 *whh  = ws + o; o += WHN;
    u16 *woh  = ws + o; o += WON;
    u16 *woth = ws + o; o += WON;
    u16 *wlh  = ws + o; o += W3N;
    u16 *wloh = ws + o; o += W3N;
    u16 *Opart = ws + o; o += NPART * NZ * SDIM * DDIM;          // bf16
    float *Lpart = (float*)(ws + o); o += 2 * NPART * NZ * SDIM;
    // total < 184 MB

    // ---- one-time: splits (weights: h-plane only) ----
    split_k<<<2048, 256, 0, stream>>>(x, curh, curl, N2 / 4);
    splith_k<<<3072, 256, 0, stream>>>(Wqkv, wqh, W3N / 4);
    split3_k<<<48, 256, 0, stream>>>(Wq, Wk, Wv, whh);
    splith_k<<<1024, 256, 0, stream>>>(Wout, woh, WON / 4);
    splith_k<<<3072, 256, 0, stream>>>(Wlayers, wlh, W3N / 4);

    // ---- one-time: transposes (h-planes only) ----
    transpose_g<<<dim3(48, 16, 1), 256, 0, stream>>>(wqh, wqth, EDIM, 3 * EDIM, 0, 0);
    transpose_g<<<dim3(16, 16, 1), 256, 0, stream>>>(woh, woth, EDIM, EDIM, 0, 0);

    // ---- one-time: Wfused = blockdiag(Wq,Wk,Wv) @ Wqkv  (single-bf16) ----
    gemm_t<128, 0><<<dim3(8, 2, 24), 256, 0, stream>>>(
        whh, 0, DDIM, (long long)DDIM * DDIM, 0, 0,
        wqth, 0, 3 * EDIM, EDIM, 0, DDIM,
        wfh, wfh, nullptr, 0, EDIM, (long long)EDIM * EDIM, 0, (long long)DDIM * EDIM,
        1, 8, DDIM, 1.0f, 0, 0, 0);

    // ---- one-time: Wlo[l] = Wlayers[l] @ Wout  (single-bf16) ----
    gemm_t<64, 0><<<dim3(16, 16, 3), 256, 0, stream>>>(
        wlh, 0, EDIM, EE, 0, 0,
        woth, 0, EDIM, 0, 0, 0,
        wloh, wloh, nullptr, 0, EDIM, EE, 0, 0,
        1, 1, EDIM, 1.0f, 0, 0, 0);

    for (int layer = 0; layer < LNUM; layer++) {
        // qkv fused + epilogue expmap (q scaled by SCALE*log2e) + V->Vt
        // transposed write (TR=1, zp==2): M=1024(s), N=128(d), K=1024
        gemm_t<128, 1><<<dim3(1, 16, 48), 256, 0, stream>>>(
            curh, 0, EDIM, 0, (long long)SDIM * EDIM, 0,
            wfh, 0, EDIM, EE, 0, (long long)DDIM * EDIM,
            qkvh, qkvh, vth, 0, DDIM, N2, (long long)HDIM * SDIM * DDIM, (long long)SDIM * DDIM,
            2, 8, EDIM, 1.0f, 0, 0, 1);

        // flash split-K partials + combine -> attnout (h only)
        flash_part<<<dim3(16, NPART, NZ), 256, 0, stream>>>(
            qkvh, qkvh + N2, vth, Opart, Lpart);
        flash_combine<<<1024, 256, 0, stream>>>(Opart, Lpart, aoh);

        // cur += attnout @ Wlo[layer]^T
        gemm_t<64, 0><<<dim3(16, 32, 1), 256, 0, stream>>>(
            aoh, 0, EDIM, 0, 0, 0,
            wloh, (long long)layer * EE, EDIM, 0, 0, 0,
            curh, curl, nullptr, 0, EDIM, 0, 0, 0,
            1, 1, EDIM, 1.0f, 1, 1, 0);
    }

    out_k<<<(out_size + 255) / 256, 256, 0, stream>>>(
        curh, curl, (float*)d_out, out_size, N2);
}

// Round 15
// 352.091 us; speedup vs baseline: 1.1434x; 1.0410x over previous
//
#include <hip/hip_runtime.h>
#include <math.h>

// Problem constants (reference: B=2,S=1024,E=1024,H=8,D=128,L=3)
#define BDIM 2
#define SDIM 1024
#define EDIM 1024
#define HDIM 8
#define DDIM 128
#define LNUM 3
#define NZ 16
#define NPART 4
#define SCALE_F 0.08838834764831845f
#define QSCALE_L2E 0.12751742f     // SCALE * log2(e)
#define TWO_L2E 2.8853901f         // 2 * log2(e)

// WORLD MODEL (verified R6-R11): complex64 lowered to f32 REAL-PART-ONLY.
// Precision: residual `cur` bf16x3 (h+l); everything else single bf16.
// R12: no-max softmax + exp2; weight folds; expmap fused in qkv epilogue.
// R13/R14 (REGRESSED): cross-barrier reg prefetch (32 VGPR) spilled.
// R15 (WIN, 477): flash K/V via global_load_lds w16 + pre-swizzled source.
// R16/R17 (WIN, 422.8): 64-row gemm tiles double block count.
// R18/R19 (REG/NEUTRAL, 457): gload_lds in gemm loses to reg-staging.
// R20 (WIN, 404.7): reg-staged gemm; Opart bf16 banked.
// R21 (WIN, 377.9): BK 32->64 halves per-block barrier/drain count.
// R22 (SEVERE REG, 696.8): BK=128 staging spilled. BK=64 final.
// R23 (OK, 383.4): revert confirmed; h-only splits banked.
// R24 (REG, 402.6): flash QBLK=128 cut co-residency 4->2 blocks/CU.
// R25 (WIN, 376.9): flash QBLK=64 restored; vectorized combine banked.
// R26 (WIN, 366.5): V-transpose fused into qkv epilogue (TR=1).
// R27: (a) gemm load-early schedule: issue step i+1 loads BEFORE step i's
// MFMA phase (latency hides under 16 MFMAs; was exposed at waitcnt before
// ds_write). Staging regs (24 VGPR) now live across MFMA — permitted via
// __launch_bounds__(256,3) (VGPR cap ~170; grid is 3 blocks/CU anyway).
// Watch: WRITE_SIZE must stay ~12MB (spill tripwire). (b) merged weight
// splits into one launch (identical stores, 4 fewer launches).

typedef unsigned short u16;
typedef __attribute__((ext_vector_type(8))) short bf16x8;
typedef __attribute__((ext_vector_type(4))) float f32x4;
typedef __attribute__((address_space(3))) unsigned char lds_u8;
typedef __attribute__((address_space(1))) const unsigned char glob_u8;

__device__ __forceinline__ u16 bf16_rne(float x) {
    unsigned u = __float_as_uint(x);
    u += 0x7FFFu + ((u >> 16) & 1u);
    return (u16)(u >> 16);
}
__device__ __forceinline__ float bf16f(u16 h) {
    return __uint_as_float(((unsigned)h) << 16);
}

// ---------------------------------------------------------------------------
__global__ __launch_bounds__(256) void split_k(
    const float* __restrict__ in, u16* __restrict__ h, u16* __restrict__ l,
    long long n4)
{
    long long i = (long long)blockIdx.x * 256 + threadIdx.x;
    if (i >= n4) return;
    float4 v = ((const float4*)in)[i];
    float vv[4] = { v.x, v.y, v.z, v.w };
    u16 hh[4], ll[4];
#pragma unroll
    for (int j = 0; j < 4; j++) {
        hh[j] = bf16_rne(vv[j]);
        ll[j] = bf16_rne(vv[j] - bf16f(hh[j]));
    }
    ((uint2*)h)[i] = make_uint2((unsigned)hh[0] | ((unsigned)hh[1] << 16),
                                (unsigned)hh[2] | ((unsigned)hh[3] << 16));
    ((uint2*)l)[i] = make_uint2((unsigned)ll[0] | ((unsigned)ll[1] << 16),
                                (unsigned)ll[2] | ((unsigned)ll[3] << 16));
}

// All weight splits (h-plane only) in ONE launch. Grid 7216:
// [0,3072) Wqkv->wqh; [3072,4096) Wout->woh; [4096,7168) Wlayers->wlh;
// [7168,7216) Wq/Wk/Wv->whh (16 blocks each).
__global__ __launch_bounds__(256) void splitw_all(
    const float* __restrict__ Wqkv, const float* __restrict__ Wout,
    const float* __restrict__ Wlayers, const float* __restrict__ Wq,
    const float* __restrict__ Wk, const float* __restrict__ Wv,
    u16* __restrict__ wqh, u16* __restrict__ woh,
    u16* __restrict__ wlh, u16* __restrict__ whh)
{
    const int bx = blockIdx.x;
    const float* src;
    u16* dst;
    long long i;
    if (bx < 3072) {
        src = Wqkv; dst = wqh; i = (long long)bx * 256 + threadIdx.x;
    } else if (bx < 4096) {
        src = Wout; dst = woh; i = (long long)(bx - 3072) * 256 + threadIdx.x;
    } else if (bx < 7168) {
        src = Wlayers; dst = wlh; i = (long long)(bx - 4096) * 256 + threadIdx.x;
    } else {
        const int t = (bx - 7168) >> 4;
        src = (t == 0) ? Wq : (t == 1) ? Wk : Wv;
        dst = whh + (long long)t * 16384;
        i = (long long)((bx - 7168) & 15) * 256 + threadIdx.x;
    }
    float4 v = ((const float4*)src)[i];
    ((uint2*)dst)[i] = make_uint2(
        (unsigned)bf16_rne(v.x) | ((unsigned)bf16_rne(v.y) << 16),
        (unsigned)bf16_rne(v.z) | ((unsigned)bf16_rne(v.w) << 16));
}

// ---------------------------------------------------------------------------
// Single-bf16 GEMM, tile 64 x NT x 64 (BK=64), 256 thr (4 waves 2x2),
// acc[2][NT/32]. R27: load-early schedule — step i+1 loads issue before
// step i's MFMA phase; latency hides under MFMAs. launch_bounds(256,3)
// relaxes VGPR cap to ~170 so the 24 staging VGPRs don't spill.
// C[m,n] = alpha*sum_k A[m,k]*B[n,k] (+Ch+Cl if accum). storeL: l-plane.
// doExp (NT==128): zp==0/1 -> expmap0 per output row in-epilogue.
// TR (NT==128): zp==2 -> write transposed Vt[d][s] via LDS shuffle.
// K must be a multiple of 64.
// ---------------------------------------------------------------------------
template<int NT, int TR>
__global__ __launch_bounds__(256, 3) void gemm_t(
    const u16* __restrict__ Ah,
    long long aOff, int lda, long long aSP, long long aSB, long long aSH,
    const u16* __restrict__ Bh,
    long long bOff, int ldb, long long bSP, long long bSB, long long bSH,
    u16* __restrict__ Ch, u16* __restrict__ Cl, u16* __restrict__ Vt,
    long long cOff, int ldc, long long cSP, long long cSB, long long cSH,
    int Bdec, int Hdec, int K, float alpha, int accum, int storeL, int doExp)
{
    constexpr int NJ = NT / 32;                   // j-tiles per wave
    __shared__ __align__(16) u16 AhL[8][64][8];   // kp 0..7
    __shared__ __align__(16) u16 BhL[8][NT][8];
    __shared__ float rsum[64][2];
    __shared__ __align__(16) u16 tl[TR ? 128 * 72 : 16];  // transpose staging

    const int tid  = threadIdx.x;
    const int lane = tid & 63;
    const int wave = tid >> 6;
    const int quad = lane >> 4;
    const int l16  = lane & 15;
    const int z  = blockIdx.z;
    const int zp = z / (Bdec * Hdec);
    const int r  = z - zp * Bdec * Hdec;
    const int zb = r / Hdec, zh = r - zb * Hdec;
    const long long aBase = aOff + (long long)zp * aSP + (long long)zb * aSB + (long long)zh * aSH;
    const long long bBase = bOff + (long long)zp * bSP + (long long)zb * bSB + (long long)zh * bSH;
    const long long cBase = cOff + (long long)zp * cSP + (long long)zb * cSB + (long long)zh * cSH;
    const int bm = blockIdx.y * 64, bn = blockIdx.x * NT;
    const int wr = (wave >> 1) * 32, wc = (wave & 1) * (NT / 2);

    // A staging: two uint4/thread. row = tid>>2, k-planes (tid&3), (tid&3)+4.
    const int ar = tid >> 2, ap = tid & 3;
    const u16* gA = Ah + aBase + (long long)(bm + ar) * lda + ap * 8;

    // B staging: NT=128 -> four uint4/thread; NT=64 -> two.
    const int sm = tid >> 1, kh = (tid & 1) * 16, c0 = kh >> 3;   // NT=128
    const int br = tid >> 2, bp = tid & 3;                        // NT=64
    const u16* gB = (NT == 128)
        ? Bh + bBase + (long long)(bn + sm) * ldb + kh
        : Bh + bBase + (long long)(bn + br) * ldb + bp * 8;

    f32x4 acc[2][NJ];
#pragma unroll
    for (int i = 0; i < 2; i++)
#pragma unroll
        for (int j = 0; j < NJ; j++) {
            acc[i][j][0] = 0.f; acc[i][j][1] = 0.f;
            acc[i][j][2] = 0.f; acc[i][j][3] = 0.f;
        }

    // ---- prologue: stage k0=0 ----
    {
        uint4 a0 = *(const uint4*)(gA);
        uint4 a1 = *(const uint4*)(gA + 32);
        uint4 b0 = *(const uint4*)(gB);
        uint4 b2 = *(const uint4*)(gB + 32);
        uint4 b1, b3;
        if (NT == 128) {
            b1 = *(const uint4*)(gB + 8);
            b3 = *(const uint4*)(gB + 40);
        }
        *(uint4*)&AhL[ap][ar][0]     = a0;
        *(uint4*)&AhL[ap + 4][ar][0] = a1;
        if (NT == 128) {
            *(uint4*)&BhL[c0][sm][0]     = b0;
            *(uint4*)&BhL[c0 + 1][sm][0] = b1;
            *(uint4*)&BhL[c0 + 4][sm][0] = b2;
            *(uint4*)&BhL[c0 + 5][sm][0] = b3;
        } else {
            *(uint4*)&BhL[bp][br][0]     = b0;
            *(uint4*)&BhL[bp + 4][br][0] = b2;
        }
    }
    __syncthreads();

    for (int k0 = 0; k0 < K; k0 += 64) {
        const bool more = (k0 + 64 < K);
        uint4 a0, a1, b0, b1, b2, b3;
        if (more) {                               // issue EARLY: hides under MFMAs
            a0 = *(const uint4*)(gA + k0 + 64);
            a1 = *(const uint4*)(gA + k0 + 96);
            b0 = *(const uint4*)(gB + k0 + 64);
            b2 = *(const uint4*)(gB + k0 + 96);
            if (NT == 128) {
                b1 = *(const uint4*)(gB + k0 + 72);
                b3 = *(const uint4*)(gB + k0 + 104);
            }
        }

#pragma unroll
        for (int s = 0; s < 2; s++) {
            bf16x8 fah[2], fbh[NJ];
#pragma unroll
            for (int i = 0; i < 2; i++)
                fah[i] = *(const bf16x8*)&AhL[s * 4 + quad][wr + i * 16 + l16][0];
#pragma unroll
            for (int j = 0; j < NJ; j++)
                fbh[j] = *(const bf16x8*)&BhL[s * 4 + quad][wc + j * 16 + l16][0];
#pragma unroll
            for (int i = 0; i < 2; i++)
#pragma unroll
                for (int j = 0; j < NJ; j++)
                    acc[i][j] = __builtin_amdgcn_mfma_f32_16x16x32_bf16(fah[i], fbh[j], acc[i][j], 0, 0, 0);
        }

        if (more) {
            __syncthreads();                      // all MFMA reads of buf done
            *(uint4*)&AhL[ap][ar][0]     = a0;
            *(uint4*)&AhL[ap + 4][ar][0] = a1;
            if (NT == 128) {
                *(uint4*)&BhL[c0][sm][0]     = b0;
                *(uint4*)&BhL[c0 + 1][sm][0] = b1;
                *(uint4*)&BhL[c0 + 4][sm][0] = b2;
                *(uint4*)&BhL[c0 + 5][sm][0] = b3;
            } else {
                *(uint4*)&BhL[bp][br][0]     = b0;
                *(uint4*)&BhL[bp + 4][br][0] = b2;
            }
            __syncthreads();                      // writes visible
        }
    }

    // ---- TR path: zp==2 (V slice) -> write transposed Vt[d][s] ----
    if (TR && zp == 2) {
        __syncthreads();                          // all waves past MFMA phase
#pragma unroll
        for (int i = 0; i < 2; i++)
#pragma unroll
            for (int j = 0; j < NJ; j++)
#pragma unroll
                for (int rr = 0; rr < 4; rr++) {
                    int ml = wr + i * 16 + quad * 4 + rr;   // s (0..63)
                    int nl = wc + j * 16 + l16;             // d (0..127)
                    tl[nl * 72 + ml] = bf16_rne(acc[i][j][rr] * alpha);
                }
        __syncthreads();
        const long long vtBase = ((long long)zb * 8 + zh) * SDIM * DDIM;
        const int rn = tid >> 1, ms = (tid & 1) * 32;
        u16* po = Vt + vtBase + (long long)rn * SDIM + bm + ms;
        const u16* ps = &tl[rn * 72 + ms];
        *(uint4*)(po)      = *(const uint4*)(ps);
        *(uint4*)(po + 8)  = *(const uint4*)(ps + 8);
        *(uint4*)(po + 16) = *(const uint4*)(ps + 16);
        *(uint4*)(po + 24) = *(const uint4*)(ps + 24);
        return;
    }

    // ---- optional fused expmap0 (q/k slices of the qkv projection) ----
    if (NT == 128 && doExp && zp < 2) {
        const float qs = (zp == 0) ? QSCALE_L2E : 1.0f;
#pragma unroll
        for (int i = 0; i < 2; i++)
#pragma unroll
            for (int rr = 0; rr < 4; rr++) {
                float ps = 0.f;
#pragma unroll
                for (int j = 0; j < NJ; j++) {
                    float v = acc[i][j][rr];
                    ps += v * v;
                }
                ps += __shfl_xor(ps, 1, 64); ps += __shfl_xor(ps, 2, 64);
                ps += __shfl_xor(ps, 4, 64); ps += __shfl_xor(ps, 8, 64);
                if (l16 == 0) rsum[wr + i * 16 + quad * 4 + rr][wc >> 6] = ps;
            }
        __syncthreads();
#pragma unroll
        for (int i = 0; i < 2; i++)
#pragma unroll
            for (int rr = 0; rr < 4; rr++) {
                int m = wr + i * 16 + quad * 4 + rr;
                float n2 = rsum[m][0] + rsum[m][1];
                float nn = fmaxf(sqrtf(n2), 1e-6f);
                float e2 = exp2f(TWO_L2E * nn);          // e^{2n}
                float scl = (1.f - 2.f / (e2 + 1.f)) / nn * qs;  // tanh(n)/n * qs
#pragma unroll
                for (int j = 0; j < NJ; j++) acc[i][j][rr] *= scl;
            }
    }

#pragma unroll
    for (int i = 0; i < 2; i++)
#pragma unroll
        for (int j = 0; j < NJ; j++)
#pragma unroll
            for (int rr = 0; rr < 4; rr++) {
                int m = bm + wr + i * 16 + quad * 4 + rr;
                int n = bn + wc + j * 16 + l16;
                long long ci = cBase + (long long)m * ldc + n;
                float c = acc[i][j][rr] * alpha;
                if (accum) c += bf16f(Ch[ci]) + bf16f(Cl[ci]);
                u16 hh = bf16_rne(c);
                Ch[ci] = hh;
                if (storeL) Cl[ci] = bf16_rne(c - bf16f(hh));
            }
}

// ---------------------------------------------------------------------------
// Flash split-K partial, no-max softmax (bounded logits; Q pre-scaled by
// SCALE*log2e so P = exp2(sacc)). Emits unnormalized O_p (bf16) + l_p.
// R23 structure: QBLK=64, K/V via global_load_lds w16 + pre-swizzled src,
// 40960B LDS (4 blocks/CU), grid 1024.
// ---------------------------------------------------------------------------
__global__ __launch_bounds__(256) void flash_part(
    const u16* __restrict__ Qh, const u16* __restrict__ Kh,
    const u16* __restrict__ Vth,
    u16* __restrict__ Opart, float* __restrict__ Lpart)
{
    __shared__ __align__(16) u16 Kls[64 * 128];   // [key 64][d 128], swizzled
    __shared__ __align__(16) u16 Vls[128 * 64];   // [d 128][key 64], swizzled
    __shared__ __align__(16) u16 pls[64 * 64];    // [qrow 64][key 64], swizzled

    const int tid  = threadIdx.x;
    const int lane = tid & 63;
    const int w    = tid >> 6;
    const int quad = lane >> 4;
    const int l16  = lane & 15;
    const int z    = blockIdx.z;
    const int part = blockIdx.y;
    const int q0   = blockIdx.x * 64;
    const long long zoff = (long long)z * SDIM * DDIM;
    const int pz = part * NZ + z;
    const int sw = (l16 & 7) << 4;                // read-side swizzle (row&7)==(l16&7)

    // ---- global_load_lds staging geometry (pre-swizzled global source) ----
    const u16* kgp[4];
    const u16* vgp[4];
#pragma unroll
    for (int i = 0; i < 4; i++) {
        int rk = w * 16 + i * 4 + (lane >> 4);
        int sk = (lane & 15) ^ (rk & 7);
        kgp[i] = Kh + zoff + (long long)(part * 256 + rk) * DDIM + sk * 8;
        int rv = w * 32 + i * 8 + (lane >> 3);
        int sv = (lane & 7) ^ (rv & 7);
        vgp[i] = Vth + zoff + (long long)rv * SDIM + part * 256 + sv * 8;
    }

    const u16* qr = Qh + zoff + (long long)(q0 + w * 16 + l16) * DDIM;
    bf16x8 qf[4];
#pragma unroll
    for (int s = 0; s < 4; s++) qf[s] = *(const bf16x8*)(qr + s * 32 + quad * 8);

    f32x4 oacc[8];
#pragma unroll
    for (int dt = 0; dt < 8; dt++) {
        oacc[dt][0] = 0.f; oacc[dt][1] = 0.f; oacc[dt][2] = 0.f; oacc[dt][3] = 0.f;
    }
    float lp[4] = { 0.f, 0.f, 0.f, 0.f };

    for (int ti = 0; ti < 4; ti++) {
        __syncthreads();                          // prior compute done reading LDS
#pragma unroll
        for (int i = 0; i < 4; i++) {
            __builtin_amdgcn_global_load_lds(
                (glob_u8*)kgp[i], (lds_u8*)&Kls[w * 2048 + i * 512], 16, 0, 0);
            __builtin_amdgcn_global_load_lds(
                (glob_u8*)vgp[i], (lds_u8*)&Vls[w * 2048 + i * 512], 16, 0, 0);
            kgp[i] += 64 * DDIM;                  // next key-tile (K rows)
            vgp[i] += 64;                         // next key-tile (V cols)
        }
        __syncthreads();                          // vmcnt(0) drained -> tiles visible

        // ---- QK^T ----
        f32x4 sacc[4];
        __builtin_amdgcn_s_setprio(1);
#pragma unroll
        for (int ct = 0; ct < 4; ct++) {
            f32x4 a; a[0] = 0.f; a[1] = 0.f; a[2] = 0.f; a[3] = 0.f;
            const char* kb_row = (const char*)Kls + (ct * 16 + l16) * 256;
#pragma unroll
            for (int s = 0; s < 4; s++) {
                bf16x8 kb = *(const bf16x8*)(kb_row + (((s * 64) | (quad * 16)) ^ sw));
                a = __builtin_amdgcn_mfma_f32_16x16x32_bf16(qf[s], kb, a, 0, 0, 0);
            }
            sacc[ct] = a;
        }
        __builtin_amdgcn_s_setprio(0);

        // P = exp2(sacc); accumulate per-thread row partials (no max needed)
#pragma unroll
        for (int ct = 0; ct < 4; ct++)
#pragma unroll
            for (int r = 0; r < 4; r++) {
                float p = exp2f(sacc[ct][r]);
                lp[r] += p;
                int prow = w * 16 + quad * 4 + r;
                int pcol = ct * 16 + l16;
                *(u16*)((char*)pls + prow * 128 + ((pcol * 2) ^ ((prow & 7) << 4))) = bf16_rne(p);
            }

        bf16x8 pa[2];
        {
            const char* p_row = (const char*)pls + (w * 16 + l16) * 128;
#pragma unroll
            for (int ks2 = 0; ks2 < 2; ks2++)
                pa[ks2] = *(const bf16x8*)(p_row + (((ks2 * 64) | (quad * 16)) ^ sw));
        }

        // ---- PV ----
        __builtin_amdgcn_s_setprio(1);
#pragma unroll
        for (int dt = 0; dt < 8; dt++) {
            f32x4 o = oacc[dt];
            const char* v_row = (const char*)Vls + (dt * 16 + l16) * 128;
#pragma unroll
            for (int ks2 = 0; ks2 < 2; ks2++) {
                bf16x8 vb = *(const bf16x8*)(v_row + (((ks2 * 64) | (quad * 16)) ^ sw));
                o = __builtin_amdgcn_mfma_f32_16x16x32_bf16(pa[ks2], vb, o, 0, 0, 0);
            }
            oacc[dt] = o;
        }
        __builtin_amdgcn_s_setprio(0);
    }

    const long long obase = (long long)pz * SDIM * DDIM;
#pragma unroll
    for (int dt = 0; dt < 8; dt++)
#pragma unroll
        for (int r = 0; r < 4; r++) {
            int srow = q0 + w * 16 + quad * 4 + r;
            Opart[obase + (long long)srow * DDIM + dt * 16 + l16] = bf16_rne(oacc[dt][r]);
        }
#pragma unroll
    for (int r = 0; r < 4; r++) {
        float s = lp[r];
        s += __shfl_xor(s, 1, 64); s += __shfl_xor(s, 2, 64);
        s += __shfl_xor(s, 4, 64); s += __shfl_xor(s, 8, 64);
        if (l16 == 0) {
            int srow = q0 + w * 16 + quad * 4 + r;
            Lpart[(long long)pz * SDIM + srow] = s;
        }
    }
}

// ---------------------------------------------------------------------------
// Combine: O = sum_p O_p / sum_p l_p. Vectorized: 8 elem/thread (bf16x8).
// grid 1024 x 256 thr; thread i -> row i/16, d-slice (i%16)*8.
// ---------------------------------------------------------------------------
__global__ __launch_bounds__(256) void flash_combine(
    const u16* __restrict__ Opart, const float* __restrict__ Lpart,
    u16* __restrict__ Oh)
{
    const long long i = (long long)blockIdx.x * 256 + threadIdx.x;  // 0..262143
    const int rg = (int)(i >> 4);                 // 0..16383 = z*1024+row
    const int z = rg >> 10, row = rg & 1023;
    const int d0 = ((int)i & 15) * 8;
    float lt = 0.f;
#pragma unroll
    for (int p = 0; p < NPART; p++)
        lt += Lpart[(long long)(p * NZ + z) * SDIM + row];
    const float inv = 1.f / lt;
    float o[8] = { 0.f, 0.f, 0.f, 0.f, 0.f, 0.f, 0.f, 0.f };
#pragma unroll
    for (int p = 0; p < NPART; p++) {
        bf16x8 v = *(const bf16x8*)&Opart[
            (long long)(p * NZ + z) * SDIM * DDIM + (long long)row * DDIM + d0];
#pragma unroll
        for (int j = 0; j < 8; j++) o[j] += bf16f((u16)v[j]);
    }
    unsigned w4[4];
#pragma unroll
    for (int j = 0; j < 4; j++)
        w4[j] = (unsigned)bf16_rne(o[2 * j] * inv)
              | ((unsigned)bf16_rne(o[2 * j + 1] * inv) << 16);
    const int b = z >> 3, h = z & 7;
    *(uint4*)&Oh[(long long)b * SDIM * EDIM + (long long)row * EDIM + h * DDIM + d0] =
        make_uint4(w4[0], w4[1], w4[2], w4[3]);
}

// ---------------------------------------------------------------------------
// Generic 64x64-tile transpose. grid (rT, cT, nz).  (one-time weights only)
// ---------------------------------------------------------------------------
__global__ __launch_bounds__(256) void transpose_g(
    const u16* __restrict__ src, u16* __restrict__ dst,
    int ldS, int ldD, long long sZ, long long dZ)
{
    __shared__ __align__(16) u16 tl[64][72];
    const int r0 = blockIdx.x * 64, c0 = blockIdx.y * 64;
    const u16* s = src + (long long)blockIdx.z * sZ;
    u16* d = dst + (long long)blockIdx.z * dZ;
    const int t = threadIdx.x;
    const int sr = t >> 2, dc = (t & 3) * 16;
    {
        const u16* p = s + (long long)(r0 + sr) * ldS + c0 + dc;
        *(uint4*)&tl[sr][dc]     = *(const uint4*)p;
        *(uint4*)&tl[sr][dc + 8] = *(const uint4*)(p + 8);
    }
    __syncthreads();
    const int dr = t >> 2, sc = (t & 3) * 16;
    unsigned wbuf[8];
#pragma unroll
    for (int i = 0; i < 8; i++)
        wbuf[i] = (unsigned)tl[sc + 2 * i][dr] | ((unsigned)tl[sc + 2 * i + 1][dr] << 16);
    u16* po = d + (long long)(c0 + dr) * ldD + r0 + sc;
    *(uint4*)po = make_uint4(wbuf[0], wbuf[1], wbuf[2], wbuf[3]);
    *(uint4*)(po + 8) = make_uint4(wbuf[4], wbuf[5], wbuf[6], wbuf[7]);
}

// final output: f32 = h + l (zero-fill past nmax)
__global__ __launch_bounds__(256) void out_k(
    const u16* __restrict__ h, const u16* __restrict__ l,
    float* __restrict__ out, long long n, long long nmax)
{
    long long i = (long long)blockIdx.x * 256 + threadIdx.x;
    if (i < n) out[i] = (i < nmax) ? (bf16f(h[i]) + bf16f(l[i])) : 0.f;
}

#define N2   2097152LL            // B*S*E == NZ*S*D
#define W3N  3145728LL            // 3E*E
#define WON  1048576LL            // E*E
#define WHN  49152LL              // 3*D*D
#define EE   1048576LL            // E*E

extern "C" void kernel_launch(void* const* d_in, const int* in_sizes, int n_in,
                              void* d_out, int out_size, void* d_ws, size_t ws_size,
                              hipStream_t stream)
{
    const float* x       = (const float*)d_in[0];
    const float* Wqkv    = (const float*)d_in[1];
    const float* Wq      = (const float*)d_in[3];
    const float* Wk      = (const float*)d_in[5];
    const float* Wv      = (const float*)d_in[7];
    const float* Wout    = (const float*)d_in[9];
    const float* Wlayers = (const float*)d_in[11];

    u16* ws = (u16*)d_ws;
    long long o = 0;
    u16 *curh = ws + o; o += N2;  u16 *curl = ws + o; o += N2;
    u16 *qkvh = ws + o; o += 3 * N2;
    u16 *vth  = ws + o; o += N2;
    u16 *aoh  = ws + o; o += N2;
    u16 *wqh  = ws + o; o += W3N;
    u16 *wqth = ws + o; o += W3N;
    u16 *wfh  = ws + o; o += W3N;
    u16 *whh  = ws + o; o += WHN;
    u16 *woh  = ws + o; o += WON;
    u16 *woth = ws + o; o += WON;
    u16 *wlh  = ws + o; o += W3N;
    u16 *wloh = ws + o; o += W3N;
    u16 *Opart = ws + o; o += NPART * NZ * SDIM * DDIM;          // bf16
    float *Lpart = (float*)(ws + o); o += 2 * NPART * NZ * SDIM;
    // total < 184 MB

    // ---- one-time: splits (x: h+l; weights: h-plane only, one launch) ----
    split_k<<<2048, 256, 0, stream>>>(x, curh, curl, N2 / 4);
    splitw_all<<<7216, 256, 0, stream>>>(Wqkv, Wout, Wlayers, Wq, Wk, Wv,
                                         wqh, woh, wlh, whh);

    // ---- one-time: transposes (h-planes only) ----
    transpose_g<<<dim3(48, 16, 1), 256, 0, stream>>>(wqh, wqth, EDIM, 3 * EDIM, 0, 0);
    transpose_g<<<dim3(16, 16, 1), 256, 0, stream>>>(woh, woth, EDIM, EDIM, 0, 0);

    // ---- one-time: Wfused = blockdiag(Wq,Wk,Wv) @ Wqkv  (single-bf16) ----
    gemm_t<128, 0><<<dim3(8, 2, 24), 256, 0, stream>>>(
        whh, 0, DDIM, (long long)DDIM * DDIM, 0, 0,
        wqth, 0, 3 * EDIM, EDIM, 0, DDIM,
        wfh, wfh, nullptr, 0, EDIM, (long long)EDIM * EDIM, 0, (long long)DDIM * EDIM,
        1, 8, DDIM, 1.0f, 0, 0, 0);

    // ---- one-time: Wlo[l] = Wlayers[l] @ Wout  (single-bf16) ----
    gemm_t<64, 0><<<dim3(16, 16, 3), 256, 0, stream>>>(
        wlh, 0, EDIM, EE, 0, 0,
        woth, 0, EDIM, 0, 0, 0,
        wloh, wloh, nullptr, 0, EDIM, EE, 0, 0,
        1, 1, EDIM, 1.0f, 0, 0, 0);

    for (int layer = 0; layer < LNUM; layer++) {
        // qkv fused + epilogue expmap (q scaled by SCALE*log2e) + V->Vt
        // transposed write (TR=1, zp==2): M=1024(s), N=128(d), K=1024
        gemm_t<128, 1><<<dim3(1, 16, 48), 256, 0, stream>>>(
            curh, 0, EDIM, 0, (long long)SDIM * EDIM, 0,
            wfh, 0, EDIM, EE, 0, (long long)DDIM * EDIM,
            qkvh, qkvh, vth, 0, DDIM, N2, (long long)HDIM * SDIM * DDIM, (long long)SDIM * DDIM,
            2, 8, EDIM, 1.0f, 0, 0, 1);

        // flash split-K partials + combine -> attnout (h only)
        flash_part<<<dim3(16, NPART, NZ), 256, 0, stream>>>(
            qkvh, qkvh + N2, vth, Opart, Lpart);
        flash_combine<<<1024, 256, 0, stream>>>(Opart, Lpart, aoh);

        // cur += attnout @ Wlo[layer]^T
        gemm_t<64, 0><<<dim3(16, 32, 1), 256, 0, stream>>>(
            aoh, 0, EDIM, 0, 0, 0,
            wloh, (long long)layer * EE, EDIM, 0, 0, 0,
            curh, curl, nullptr, 0, EDIM, 0, 0, 0,
            1, 1, EDIM, 1.0f, 1, 1, 0);
    }

    out_k<<<(out_size + 255) / 256, 256, 0, stream>>>(
        curh, curl, (float*)d_out, out_size, N2);
}

// Round 16
// 348.962 us; speedup vs baseline: 1.1537x; 1.0090x over previous
//
#include <hip/hip_runtime.h>
#include <math.h>

// Problem constants (reference: B=2,S=1024,E=1024,H=8,D=128,L=3)
#define BDIM 2
#define SDIM 1024
#define EDIM 1024
#define HDIM 8
#define DDIM 128
#define LNUM 3
#define NZ 16
#define NPART 4
#define SCALE_F 0.08838834764831845f
#define QSCALE_L2E 0.12751742f     // SCALE * log2(e)
#define TWO_L2E 2.8853901f         // 2 * log2(e)

// WORLD MODEL (verified R6-R11): complex64 lowered to f32 REAL-PART-ONLY.
// Precision: residual `cur` bf16x3 (h+l); everything else single bf16.
// R12: no-max softmax + exp2; weight folds; expmap fused in qkv epilogue.
// R13/R14 (REG): cross-barrier reg prefetch spilled (allocator target).
// R15 (WIN, 477): flash K/V via global_load_lds w16 + pre-swizzled source.
// R16/R17 (WIN, 422.8): 64-row gemm tiles double block count.
// R18/R19 (REG/NEUTRAL, 457): gload_lds in gemm loses to reg-staging.
// R20 (WIN, 404.7): reg-staged gemm; Opart bf16 banked.
// R21 (WIN, 377.9): BK 32->64. R22 (REG, 696.8): BK=128 spilled. BK=64.
// R23 (OK, 383.4): revert confirmed. R24 (REG, 402.6): flash QBLK=128 cut
// co-residency 4->2/CU. R25 (WIN, 376.9): QBLK=64 + vec combine.
// R26 (WIN, 366.5): V-transpose fused into qkv epilogue (TR=1).
// R27 (WIN, 352.1): gemm load-early + launch_bounds(256,3) (no spill —
// relaxing the allocator's occupancy target was the fix); merged splits.
// R28: (a) flash split-stage schedule: stage K[ti+1] right after QK^T's
// barrier (hides under exp/pls/PV), stage V[ti+1] after PV's barrier
// (hides under next QK^T). Same 2 barriers/ti, zero extra LDS/regs,
// 4 blocks/CU preserved. (b) fused split+transpose (splitT_k) for
// Wqkv->wqth, Wout->woth: kills wqh/woh + 2 launches + ~28MB traffic.

typedef unsigned short u16;
typedef __attribute__((ext_vector_type(8))) short bf16x8;
typedef __attribute__((ext_vector_type(4))) float f32x4;
typedef __attribute__((address_space(3))) unsigned char lds_u8;
typedef __attribute__((address_space(1))) const unsigned char glob_u8;

__device__ __forceinline__ u16 bf16_rne(float x) {
    unsigned u = __float_as_uint(x);
    u += 0x7FFFu + ((u >> 16) & 1u);
    return (u16)(u >> 16);
}
__device__ __forceinline__ float bf16f(u16 h) {
    return __uint_as_float(((unsigned)h) << 16);
}

// ---------------------------------------------------------------------------
__global__ __launch_bounds__(256) void split_k(
    const float* __restrict__ in, u16* __restrict__ h, u16* __restrict__ l,
    long long n4)
{
    long long i = (long long)blockIdx.x * 256 + threadIdx.x;
    if (i >= n4) return;
    float4 v = ((const float4*)in)[i];
    float vv[4] = { v.x, v.y, v.z, v.w };
    u16 hh[4], ll[4];
#pragma unroll
    for (int j = 0; j < 4; j++) {
        hh[j] = bf16_rne(vv[j]);
        ll[j] = bf16_rne(vv[j] - bf16f(hh[j]));
    }
    ((uint2*)h)[i] = make_uint2((unsigned)hh[0] | ((unsigned)hh[1] << 16),
                                (unsigned)hh[2] | ((unsigned)hh[3] << 16));
    ((uint2*)l)[i] = make_uint2((unsigned)ll[0] | ((unsigned)ll[1] << 16),
                                (unsigned)ll[2] | ((unsigned)ll[3] << 16));
}

// Remaining weight splits (h-plane only), one launch. Grid 3120:
// [0,3072) Wlayers->wlh; [3072,3120) Wq/Wk/Wv->whh (16 blocks each).
__global__ __launch_bounds__(256) void splitw_all(
    const float* __restrict__ Wlayers, const float* __restrict__ Wq,
    const float* __restrict__ Wk, const float* __restrict__ Wv,
    u16* __restrict__ wlh, u16* __restrict__ whh)
{
    const int bx = blockIdx.x;
    const float* src;
    u16* dst;
    long long i;
    if (bx < 3072) {
        src = Wlayers; dst = wlh; i = (long long)bx * 256 + threadIdx.x;
    } else {
        const int t = (bx - 3072) >> 4;
        src = (t == 0) ? Wq : (t == 1) ? Wk : Wv;
        dst = whh + (long long)t * 16384;
        i = (long long)((bx - 3072) & 15) * 256 + threadIdx.x;
    }
    float4 v = ((const float4*)src)[i];
    ((uint2*)dst)[i] = make_uint2(
        (unsigned)bf16_rne(v.x) | ((unsigned)bf16_rne(v.y) << 16),
        (unsigned)bf16_rne(v.z) | ((unsigned)bf16_rne(v.w) << 16));
}

// Fused split+transpose: read f32 src (ldS), write bf16 dst TRANSPOSED (ldD).
// 64x64 tiles, grid (rTiles, cTiles).
__global__ __launch_bounds__(256) void splitT_k(
    const float* __restrict__ src, u16* __restrict__ dst, int ldS, int ldD)
{
    __shared__ __align__(16) u16 tl[64][72];
    const int r0 = blockIdx.x * 64, c0 = blockIdx.y * 64;
    const int t = threadIdx.x;
    const int sr = t >> 2, dc = (t & 3) * 16;
    const float* p = src + (long long)(r0 + sr) * ldS + c0 + dc;
#pragma unroll
    for (int q = 0; q < 4; q++) {
        float4 v = *(const float4*)(p + q * 4);
        tl[sr][dc + q * 4 + 0] = bf16_rne(v.x);
        tl[sr][dc + q * 4 + 1] = bf16_rne(v.y);
        tl[sr][dc + q * 4 + 2] = bf16_rne(v.z);
        tl[sr][dc + q * 4 + 3] = bf16_rne(v.w);
    }
    __syncthreads();
    const int dr = t >> 2, sc = (t & 3) * 16;
    unsigned wbuf[8];
#pragma unroll
    for (int i = 0; i < 8; i++)
        wbuf[i] = (unsigned)tl[sc + 2 * i][dr] | ((unsigned)tl[sc + 2 * i + 1][dr] << 16);
    u16* po = dst + (long long)(c0 + dr) * ldD + r0 + sc;
    *(uint4*)po = make_uint4(wbuf[0], wbuf[1], wbuf[2], wbuf[3]);
    *(uint4*)(po + 8) = make_uint4(wbuf[4], wbuf[5], wbuf[6], wbuf[7]);
}

// ---------------------------------------------------------------------------
// Single-bf16 GEMM, tile 64 x NT x 64 (BK=64), 256 thr (4 waves 2x2),
// acc[2][NT/32]. R27 load-early schedule; launch_bounds(256,3).
// C[m,n] = alpha*sum_k A[m,k]*B[n,k] (+Ch+Cl if accum). storeL: l-plane.
// doExp (NT==128): zp==0/1 -> expmap0 per output row in-epilogue.
// TR (NT==128): zp==2 -> write transposed Vt[d][s] via LDS shuffle.
// K must be a multiple of 64.
// ---------------------------------------------------------------------------
template<int NT, int TR>
__global__ __launch_bounds__(256, 3) void gemm_t(
    const u16* __restrict__ Ah,
    long long aOff, int lda, long long aSP, long long aSB, long long aSH,
    const u16* __restrict__ Bh,
    long long bOff, int ldb, long long bSP, long long bSB, long long bSH,
    u16* __restrict__ Ch, u16* __restrict__ Cl, u16* __restrict__ Vt,
    long long cOff, int ldc, long long cSP, long long cSB, long long cSH,
    int Bdec, int Hdec, int K, float alpha, int accum, int storeL, int doExp)
{
    constexpr int NJ = NT / 32;                   // j-tiles per wave
    __shared__ __align__(16) u16 AhL[8][64][8];   // kp 0..7
    __shared__ __align__(16) u16 BhL[8][NT][8];
    __shared__ float rsum[64][2];
    __shared__ __align__(16) u16 tl[TR ? 128 * 72 : 16];  // transpose staging

    const int tid  = threadIdx.x;
    const int lane = tid & 63;
    const int wave = tid >> 6;
    const int quad = lane >> 4;
    const int l16  = lane & 15;
    const int z  = blockIdx.z;
    const int zp = z / (Bdec * Hdec);
    const int r  = z - zp * Bdec * Hdec;
    const int zb = r / Hdec, zh = r - zb * Hdec;
    const long long aBase = aOff + (long long)zp * aSP + (long long)zb * aSB + (long long)zh * aSH;
    const long long bBase = bOff + (long long)zp * bSP + (long long)zb * bSB + (long long)zh * bSH;
    const long long cBase = cOff + (long long)zp * cSP + (long long)zb * cSB + (long long)zh * cSH;
    const int bm = blockIdx.y * 64, bn = blockIdx.x * NT;
    const int wr = (wave >> 1) * 32, wc = (wave & 1) * (NT / 2);

    // A staging: two uint4/thread. row = tid>>2, k-planes (tid&3), (tid&3)+4.
    const int ar = tid >> 2, ap = tid & 3;
    const u16* gA = Ah + aBase + (long long)(bm + ar) * lda + ap * 8;

    // B staging: NT=128 -> four uint4/thread; NT=64 -> two.
    const int sm = tid >> 1, kh = (tid & 1) * 16, c0 = kh >> 3;   // NT=128
    const int br = tid >> 2, bp = tid & 3;                        // NT=64
    const u16* gB = (NT == 128)
        ? Bh + bBase + (long long)(bn + sm) * ldb + kh
        : Bh + bBase + (long long)(bn + br) * ldb + bp * 8;

    f32x4 acc[2][NJ];
#pragma unroll
    for (int i = 0; i < 2; i++)
#pragma unroll
        for (int j = 0; j < NJ; j++) {
            acc[i][j][0] = 0.f; acc[i][j][1] = 0.f;
            acc[i][j][2] = 0.f; acc[i][j][3] = 0.f;
        }

    // ---- prologue: stage k0=0 ----
    {
        uint4 a0 = *(const uint4*)(gA);
        uint4 a1 = *(const uint4*)(gA + 32);
        uint4 b0 = *(const uint4*)(gB);
        uint4 b2 = *(const uint4*)(gB + 32);
        uint4 b1, b3;
        if (NT == 128) {
            b1 = *(const uint4*)(gB + 8);
            b3 = *(const uint4*)(gB + 40);
        }
        *(uint4*)&AhL[ap][ar][0]     = a0;
        *(uint4*)&AhL[ap + 4][ar][0] = a1;
        if (NT == 128) {
            *(uint4*)&BhL[c0][sm][0]     = b0;
            *(uint4*)&BhL[c0 + 1][sm][0] = b1;
            *(uint4*)&BhL[c0 + 4][sm][0] = b2;
            *(uint4*)&BhL[c0 + 5][sm][0] = b3;
        } else {
            *(uint4*)&BhL[bp][br][0]     = b0;
            *(uint4*)&BhL[bp + 4][br][0] = b2;
        }
    }
    __syncthreads();

    for (int k0 = 0; k0 < K; k0 += 64) {
        const bool more = (k0 + 64 < K);
        uint4 a0, a1, b0, b1, b2, b3;
        if (more) {                               // issue EARLY: hides under MFMAs
            a0 = *(const uint4*)(gA + k0 + 64);
            a1 = *(const uint4*)(gA + k0 + 96);
            b0 = *(const uint4*)(gB + k0 + 64);
            b2 = *(const uint4*)(gB + k0 + 96);
            if (NT == 128) {
                b1 = *(const uint4*)(gB + k0 + 72);
                b3 = *(const uint4*)(gB + k0 + 104);
            }
        }

#pragma unroll
        for (int s = 0; s < 2; s++) {
            bf16x8 fah[2], fbh[NJ];
#pragma unroll
            for (int i = 0; i < 2; i++)
                fah[i] = *(const bf16x8*)&AhL[s * 4 + quad][wr + i * 16 + l16][0];
#pragma unroll
            for (int j = 0; j < NJ; j++)
                fbh[j] = *(const bf16x8*)&BhL[s * 4 + quad][wc + j * 16 + l16][0];
#pragma unroll
            for (int i = 0; i < 2; i++)
#pragma unroll
                for (int j = 0; j < NJ; j++)
                    acc[i][j] = __builtin_amdgcn_mfma_f32_16x16x32_bf16(fah[i], fbh[j], acc[i][j], 0, 0, 0);
        }

        if (more) {
            __syncthreads();                      // all MFMA reads of buf done
            *(uint4*)&AhL[ap][ar][0]     = a0;
            *(uint4*)&AhL[ap + 4][ar][0] = a1;
            if (NT == 128) {
                *(uint4*)&BhL[c0][sm][0]     = b0;
                *(uint4*)&BhL[c0 + 1][sm][0] = b1;
                *(uint4*)&BhL[c0 + 4][sm][0] = b2;
                *(uint4*)&BhL[c0 + 5][sm][0] = b3;
            } else {
                *(uint4*)&BhL[bp][br][0]     = b0;
                *(uint4*)&BhL[bp + 4][br][0] = b2;
            }
            __syncthreads();                      // writes visible
        }
    }

    // ---- TR path: zp==2 (V slice) -> write transposed Vt[d][s] ----
    if (TR && zp == 2) {
        __syncthreads();                          // all waves past MFMA phase
#pragma unroll
        for (int i = 0; i < 2; i++)
#pragma unroll
            for (int j = 0; j < NJ; j++)
#pragma unroll
                for (int rr = 0; rr < 4; rr++) {
                    int ml = wr + i * 16 + quad * 4 + rr;   // s (0..63)
                    int nl = wc + j * 16 + l16;             // d (0..127)
                    tl[nl * 72 + ml] = bf16_rne(acc[i][j][rr] * alpha);
                }
        __syncthreads();
        const long long vtBase = ((long long)zb * 8 + zh) * SDIM * DDIM;
        const int rn = tid >> 1, ms = (tid & 1) * 32;
        u16* po = Vt + vtBase + (long long)rn * SDIM + bm + ms;
        const u16* ps = &tl[rn * 72 + ms];
        *(uint4*)(po)      = *(const uint4*)(ps);
        *(uint4*)(po + 8)  = *(const uint4*)(ps + 8);
        *(uint4*)(po + 16) = *(const uint4*)(ps + 16);
        *(uint4*)(po + 24) = *(const uint4*)(ps + 24);
        return;
    }

    // ---- optional fused expmap0 (q/k slices of the qkv projection) ----
    if (NT == 128 && doExp && zp < 2) {
        const float qs = (zp == 0) ? QSCALE_L2E : 1.0f;
#pragma unroll
        for (int i = 0; i < 2; i++)
#pragma unroll
            for (int rr = 0; rr < 4; rr++) {
                float ps = 0.f;
#pragma unroll
                for (int j = 0; j < NJ; j++) {
                    float v = acc[i][j][rr];
                    ps += v * v;
                }
                ps += __shfl_xor(ps, 1, 64); ps += __shfl_xor(ps, 2, 64);
                ps += __shfl_xor(ps, 4, 64); ps += __shfl_xor(ps, 8, 64);
                if (l16 == 0) rsum[wr + i * 16 + quad * 4 + rr][wc >> 6] = ps;
            }
        __syncthreads();
#pragma unroll
        for (int i = 0; i < 2; i++)
#pragma unroll
            for (int rr = 0; rr < 4; rr++) {
                int m = wr + i * 16 + quad * 4 + rr;
                float n2 = rsum[m][0] + rsum[m][1];
                float nn = fmaxf(sqrtf(n2), 1e-6f);
                float e2 = exp2f(TWO_L2E * nn);          // e^{2n}
                float scl = (1.f - 2.f / (e2 + 1.f)) / nn * qs;  // tanh(n)/n * qs
#pragma unroll
                for (int j = 0; j < NJ; j++) acc[i][j][rr] *= scl;
            }
    }

#pragma unroll
    for (int i = 0; i < 2; i++)
#pragma unroll
        for (int j = 0; j < NJ; j++)
#pragma unroll
            for (int rr = 0; rr < 4; rr++) {
                int m = bm + wr + i * 16 + quad * 4 + rr;
                int n = bn + wc + j * 16 + l16;
                long long ci = cBase + (long long)m * ldc + n;
                float c = acc[i][j][rr] * alpha;
                if (accum) c += bf16f(Ch[ci]) + bf16f(Cl[ci]);
                u16 hh = bf16_rne(c);
                Ch[ci] = hh;
                if (storeL) Cl[ci] = bf16_rne(c - bf16f(hh));
            }
}

// ---------------------------------------------------------------------------
// Flash split-K partial, no-max softmax (bounded logits; Q pre-scaled by
// SCALE*log2e so P = exp2(sacc)). Emits unnormalized O_p (bf16) + l_p.
// R28 split-stage schedule: K[ti+1] staged after QK^T barrier (hides under
// exp/pls/PV), V[ti+1] after PV barrier (hides under next QK^T). Same
// 2 barriers/ti; QBLK=64, 40960B LDS, 4 blocks/CU (R24 lesson).
// pls write->read is intra-wave (rows w*16..) — no barrier needed there.
// ---------------------------------------------------------------------------
__global__ __launch_bounds__(256) void flash_part(
    const u16* __restrict__ Qh, const u16* __restrict__ Kh,
    const u16* __restrict__ Vth,
    u16* __restrict__ Opart, float* __restrict__ Lpart)
{
    __shared__ __align__(16) u16 Kls[64 * 128];   // [key 64][d 128], swizzled
    __shared__ __align__(16) u16 Vls[128 * 64];   // [d 128][key 64], swizzled
    __shared__ __align__(16) u16 pls[64 * 64];    // [qrow 64][key 64], swizzled

    const int tid  = threadIdx.x;
    const int lane = tid & 63;
    const int w    = tid >> 6;
    const int quad = lane >> 4;
    const int l16  = lane & 15;
    const int z    = blockIdx.z;
    const int part = blockIdx.y;
    const int q0   = blockIdx.x * 64;
    const long long zoff = (long long)z * SDIM * DDIM;
    const int pz = part * NZ + z;
    const int sw = (l16 & 7) << 4;                // read-side swizzle (row&7)==(l16&7)

    // ---- global_load_lds staging geometry (pre-swizzled global source) ----
    const u16* kgp[4];
    const u16* vgp[4];
#pragma unroll
    for (int i = 0; i < 4; i++) {
        int rk = w * 16 + i * 4 + (lane >> 4);
        int sk = (lane & 15) ^ (rk & 7);
        kgp[i] = Kh + zoff + (long long)(part * 256 + rk) * DDIM + sk * 8;
        int rv = w * 32 + i * 8 + (lane >> 3);
        int sv = (lane & 7) ^ (rv & 7);
        vgp[i] = Vth + zoff + (long long)rv * SDIM + part * 256 + sv * 8;
    }

#define STAGE_K() do {                                                        \
    _Pragma("unroll")                                                         \
    for (int i = 0; i < 4; i++) {                                             \
        __builtin_amdgcn_global_load_lds(                                     \
            (glob_u8*)kgp[i], (lds_u8*)&Kls[w * 2048 + i * 512], 16, 0, 0);   \
        kgp[i] += 64 * DDIM;                                                  \
    } } while (0)
#define STAGE_V() do {                                                        \
    _Pragma("unroll")                                                         \
    for (int i = 0; i < 4; i++) {                                             \
        __builtin_amdgcn_global_load_lds(                                     \
            (glob_u8*)vgp[i], (lds_u8*)&Vls[w * 2048 + i * 512], 16, 0, 0);   \
        vgp[i] += 64;                                                         \
    } } while (0)

    const u16* qr = Qh + zoff + (long long)(q0 + w * 16 + l16) * DDIM;
    bf16x8 qf[4];
#pragma unroll
    for (int s = 0; s < 4; s++) qf[s] = *(const bf16x8*)(qr + s * 32 + quad * 8);

    f32x4 oacc[8];
#pragma unroll
    for (int dt = 0; dt < 8; dt++) {
        oacc[dt][0] = 0.f; oacc[dt][1] = 0.f; oacc[dt][2] = 0.f; oacc[dt][3] = 0.f;
    }
    float lp[4] = { 0.f, 0.f, 0.f, 0.f };

    STAGE_K();
    STAGE_V();
    __syncthreads();                              // K0,V0 drained & visible

    for (int ti = 0; ti < 4; ti++) {
        // ---- QK^T (reads Kls[ti]; V[ti] already drained at prior barrier) ----
        f32x4 sacc[4];
        __builtin_amdgcn_s_setprio(1);
#pragma unroll
        for (int ct = 0; ct < 4; ct++) {
            f32x4 a; a[0] = 0.f; a[1] = 0.f; a[2] = 0.f; a[3] = 0.f;
            const char* kb_row = (const char*)Kls + (ct * 16 + l16) * 256;
#pragma unroll
            for (int s = 0; s < 4; s++) {
                bf16x8 kb = *(const bf16x8*)(kb_row + (((s * 64) | (quad * 16)) ^ sw));
                a = __builtin_amdgcn_mfma_f32_16x16x32_bf16(qf[s], kb, a, 0, 0, 0);
            }
            sacc[ct] = a;
        }
        __builtin_amdgcn_s_setprio(0);

        __syncthreads();                          // A: all Kls reads done; V[ti] ready
        if (ti < 3) STAGE_K();                    // K[ti+1] hides under exp/pls/PV

        // P = exp2(sacc); accumulate per-thread row partials (no max needed)
#pragma unroll
        for (int ct = 0; ct < 4; ct++)
#pragma unroll
            for (int r = 0; r < 4; r++) {
                float p = exp2f(sacc[ct][r]);
                lp[r] += p;
                int prow = w * 16 + quad * 4 + r;
                int pcol = ct * 16 + l16;
                *(u16*)((char*)pls + prow * 128 + ((pcol * 2) ^ ((prow & 7) << 4))) = bf16_rne(p);
            }

        bf16x8 pa[2];
        {
            const char* p_row = (const char*)pls + (w * 16 + l16) * 128;
#pragma unroll
            for (int ks2 = 0; ks2 < 2; ks2++)
                pa[ks2] = *(const bf16x8*)(p_row + (((ks2 * 64) | (quad * 16)) ^ sw));
        }

        // ---- PV (reads Vls[ti]) ----
        __builtin_amdgcn_s_setprio(1);
#pragma unroll
        for (int dt = 0; dt < 8; dt++) {
            f32x4 o = oacc[dt];
            const char* v_row = (const char*)Vls + (dt * 16 + l16) * 128;
#pragma unroll
            for (int ks2 = 0; ks2 < 2; ks2++) {
                bf16x8 vb = *(const bf16x8*)(v_row + (((ks2 * 64) | (quad * 16)) ^ sw));
                o = __builtin_amdgcn_mfma_f32_16x16x32_bf16(pa[ks2], vb, o, 0, 0, 0);
            }
            oacc[dt] = o;
        }
        __builtin_amdgcn_s_setprio(0);

        __syncthreads();                          // B: Vls reads done; K[ti+1] drained
        if (ti < 3) STAGE_V();                    // V[ti+1] hides under next QK^T
    }
#undef STAGE_K
#undef STAGE_V

    const long long obase = (long long)pz * SDIM * DDIM;
#pragma unroll
    for (int dt = 0; dt < 8; dt++)
#pragma unroll
        for (int r = 0; r < 4; r++) {
            int srow = q0 + w * 16 + quad * 4 + r;
            Opart[obase + (long long)srow * DDIM + dt * 16 + l16] = bf16_rne(oacc[dt][r]);
        }
#pragma unroll
    for (int r = 0; r < 4; r++) {
        float s = lp[r];
        s += __shfl_xor(s, 1, 64); s += __shfl_xor(s, 2, 64);
        s += __shfl_xor(s, 4, 64); s += __shfl_xor(s, 8, 64);
        if (l16 == 0) {
            int srow = q0 + w * 16 + quad * 4 + r;
            Lpart[(long long)pz * SDIM + srow] = s;
        }
    }
}

// ---------------------------------------------------------------------------
// Combine: O = sum_p O_p / sum_p l_p. Vectorized: 8 elem/thread (bf16x8).
// grid 1024 x 256 thr; thread i -> row i/16, d-slice (i%16)*8.
// ---------------------------------------------------------------------------
__global__ __launch_bounds__(256) void flash_combine(
    const u16* __restrict__ Opart, const float* __restrict__ Lpart,
    u16* __restrict__ Oh)
{
    const long long i = (long long)blockIdx.x * 256 + threadIdx.x;  // 0..262143
    const int rg = (int)(i >> 4);                 // 0..16383 = z*1024+row
    const int z = rg >> 10, row = rg & 1023;
    const int d0 = ((int)i & 15) * 8;
    float lt = 0.f;
#pragma unroll
    for (int p = 0; p < NPART; p++)
        lt += Lpart[(long long)(p * NZ + z) * SDIM + row];
    const float inv = 1.f / lt;
    float o[8] = { 0.f, 0.f, 0.f, 0.f, 0.f, 0.f, 0.f, 0.f };
#pragma unroll
    for (int p = 0; p < NPART; p++) {
        bf16x8 v = *(const bf16x8*)&Opart[
            (long long)(p * NZ + z) * SDIM * DDIM + (long long)row * DDIM + d0];
#pragma unroll
        for (int j = 0; j < 8; j++) o[j] += bf16f((u16)v[j]);
    }
    unsigned w4[4];
#pragma unroll
    for (int j = 0; j < 4; j++)
        w4[j] = (unsigned)bf16_rne(o[2 * j] * inv)
              | ((unsigned)bf16_rne(o[2 * j + 1] * inv) << 16);
    const int b = z >> 3, h = z & 7;
    *(uint4*)&Oh[(long long)b * SDIM * EDIM + (long long)row * EDIM + h * DDIM + d0] =
        make_uint4(w4[0], w4[1], w4[2], w4[3]);
}

// final output: f32 = h + l (zero-fill past nmax)
__global__ __launch_bounds__(256) void out_k(
    const u16* __restrict__ h, const u16* __restrict__ l,
    float* __restrict__ out, long long n, long long nmax)
{
    long long i = (long long)blockIdx.x * 256 + threadIdx.x;
    if (i < n) out[i] = (i < nmax) ? (bf16f(h[i]) + bf16f(l[i])) : 0.f;
}

#define N2   2097152LL            // B*S*E == NZ*S*D
#define W3N  3145728LL            // 3E*E
#define WON  1048576LL            // E*E
#define WHN  49152LL              // 3*D*D
#define EE   1048576LL            // E*E

extern "C" void kernel_launch(void* const* d_in, const int* in_sizes, int n_in,
                              void* d_out, int out_size, void* d_ws, size_t ws_size,
                              hipStream_t stream)
{
    const float* x       = (const float*)d_in[0];
    const float* Wqkv    = (const float*)d_in[1];
    const float* Wq      = (const float*)d_in[3];
    const float* Wk      = (const float*)d_in[5];
    const float* Wv      = (const float*)d_in[7];
    const float* Wout    = (const float*)d_in[9];
    const float* Wlayers = (const float*)d_in[11];

    u16* ws = (u16*)d_ws;
    long long o = 0;
    u16 *curh = ws + o; o += N2;  u16 *curl = ws + o; o += N2;
    u16 *qkvh = ws + o; o += 3 * N2;
    u16 *vth  = ws + o; o += N2;
    u16 *aoh  = ws + o; o += N2;
    u16 *wqth = ws + o; o += W3N;
    u16 *wfh  = ws + o; o += W3N;
    u16 *whh  = ws + o; o += WHN;
    u16 *woth = ws + o; o += WON;
    u16 *wlh  = ws + o; o += W3N;
    u16 *wloh = ws + o; o += W3N;
    u16 *Opart = ws + o; o += NPART * NZ * SDIM * DDIM;          // bf16
    float *Lpart = (float*)(ws + o); o += 2 * NPART * NZ * SDIM;
    // total < 184 MB

    // ---- one-time: splits (x: h+l; weights: h-plane only) ----
    split_k<<<2048, 256, 0, stream>>>(x, curh, curl, N2 / 4);
    splitw_all<<<3120, 256, 0, stream>>>(Wlayers, Wq, Wk, Wv, wlh, whh);
    // fused split+transpose: Wqkv -> wqth (E x 3E), Wout -> woth (E x E)
    splitT_k<<<dim3(48, 16), 256, 0, stream>>>(Wqkv, wqth, EDIM, 3 * EDIM);
    splitT_k<<<dim3(16, 16), 256, 0, stream>>>(Wout, woth, EDIM, EDIM);

    // ---- one-time: Wfused = blockdiag(Wq,Wk,Wv) @ Wqkv  (single-bf16) ----
    gemm_t<128, 0><<<dim3(8, 2, 24), 256, 0, stream>>>(
        whh, 0, DDIM, (long long)DDIM * DDIM, 0, 0,
        wqth, 0, 3 * EDIM, EDIM, 0, DDIM,
        wfh, wfh, nullptr, 0, EDIM, (long long)EDIM * EDIM, 0, (long long)DDIM * EDIM,
        1, 8, DDIM, 1.0f, 0, 0, 0);

    // ---- one-time: Wlo[l] = Wlayers[l] @ Wout  (single-bf16) ----
    gemm_t<64, 0><<<dim3(16, 16, 3), 256, 0, stream>>>(
        wlh, 0, EDIM, EE, 0, 0,
        woth, 0, EDIM, 0, 0, 0,
        wloh, wloh, nullptr, 0, EDIM, EE, 0, 0,
        1, 1, EDIM, 1.0f, 0, 0, 0);

    for (int layer = 0; layer < LNUM; layer++) {
        // qkv fused + epilogue expmap (q scaled by SCALE*log2e) + V->Vt
        // transposed write (TR=1, zp==2): M=1024(s), N=128(d), K=1024
        gemm_t<128, 1><<<dim3(1, 16, 48), 256, 0, stream>>>(
            curh, 0, EDIM, 0, (long long)SDIM * EDIM, 0,
            wfh, 0, EDIM, EE, 0, (long long)DDIM * EDIM,
            qkvh, qkvh, vth, 0, DDIM, N2, (long long)HDIM * SDIM * DDIM, (long long)SDIM * DDIM,
            2, 8, EDIM, 1.0f, 0, 0, 1);

        // flash split-K partials + combine -> attnout (h only)
        flash_part<<<dim3(16, NPART, NZ), 256, 0, stream>>>(
            qkvh, qkvh + N2, vth, Opart, Lpart);
        flash_combine<<<1024, 256, 0, stream>>>(Opart, Lpart, aoh);

        // cur += attnout @ Wlo[layer]^T
        gemm_t<64, 0><<<dim3(16, 32, 1), 256, 0, stream>>>(
            aoh, 0, EDIM, 0, 0, 0,
            wloh, (long long)layer * EE, EDIM, 0, 0, 0,
            curh, curl, nullptr, 0, EDIM, 0, 0, 0,
            1, 1, EDIM, 1.0f, 1, 1, 0);
    }

    out_k<<<(out_size + 255) / 256, 256, 0, stream>>>(
        curh, curl, (float*)d_out, out_size, N2);
}